// Round 10
// baseline (288.976 us; speedup 1.0000x reference)
//
#include <hip/hip_runtime.h>
#include <hip/hip_fp16.h>
#include <math.h>

#define LEAKY 0.2f
#define HDIM 64
#define EPB 2048            // edges per block (compute, sort, count)
#define TPB1 256
#define PERT (EPB / TPB1)   // 8 edges per thread
#define RANGE 1024          // nodes per bucket
#define RSH 10
#define KMAX 128
#define NSLICE 12
#define FIXS 4194304.0f     // 2^22 fixed-point scale
#define INVFIXS (1.0f / 4194304.0f)

// record: bits [0,11) lid, [11,27) f16 mx, [27,43) f16 my, [43,59) f16 mz

__global__ void precompute_kernel(const float* __restrict__ Wp1,
                                  const float* __restrict__ bp1,
                                  const float* __restrict__ Wp2,
                                  float* __restrict__ consts) {
    int k = threadIdx.x;  // 64 threads == HDIM == one wave
    float w1 = Wp1[k];
    float slope = (w1 >= 0.f) ? 1.f : LEAKY;
    float c = Wp2[k] * w1 * slope;
    float bnz = (bp1[k] != 0.f) ? 1.f : 0.f;
    #pragma unroll
    for (int off = 32; off > 0; off >>= 1) {
        c += __shfl_down(c, off, 64);
        bnz += __shfl_down(bnz, off, 64);
    }
    if (k == 0) { consts[0] = c; consts[1] = bnz; }
}

// tanh(v) = 1 - 2/(exp2(v*2*log2e)+1); exact saturation at +-inf, ~1e-6 rel err.
// Avoids the heavyweight ocml tanh (VGPR + VALU).
__device__ __forceinline__ float fast_tanh(float v) {
    float e = __builtin_amdgcn_exp2f(v * 2.88539008178f);
    return 1.0f - 2.0f * __builtin_amdgcn_rcpf(e + 1.0f);
}

__device__ __forceinline__ float edge_eo(float rad, float C, bool slow,
                                         const float* sW1, const float* sb1,
                                         const float* sW2) {
    if (!slow) return fast_tanh(C * rad);  // bp1==0, rad>=0: MLP collapses to linear
    float a = 0.f;
    #pragma unroll
    for (int k = 0; k < HDIM; k++) {
        float h = fmaf(rad, sW1[k], sb1[k]);
        h = (h > 0.f) ? h : LEAKY * h;
        a = fmaf(sW2[k], h, a);
    }
    return fast_tanh(a);
}

__global__ void repack_kernel(const float* __restrict__ x, float4* __restrict__ x4, int N) {
    int i = blockIdx.x * blockDim.x + threadIdx.x;
    if (i < N) x4[i] = make_float4(x[3*i], x[3*i+1], x[3*i+2], 0.f);
}

// half-packed coords: 8 B/node -> 8 nodes per 64B line (2x L1/L2 line efficiency)
__global__ void repack_h_kernel(const float* __restrict__ x, uint2* __restrict__ xh, int N) {
    int i = blockIdx.x * blockDim.x + threadIdx.x;
    if (i < N) {
        unsigned hx = __half_as_ushort(__float2half(x[3*i]));
        unsigned hy = __half_as_ushort(__float2half(x[3*i+1]));
        unsigned hz = __half_as_ushort(__float2half(x[3*i+2]));
        xh[i] = make_uint2((hy << 16) | hx, hz);
    }
}

__device__ __forceinline__ unsigned long long pack_rec(float dx, float dy, float dz,
                                                       float eo, unsigned lid) {
    unsigned hx = __half_as_ushort(__float2half(dx * eo));
    unsigned hy = __half_as_ushort(__float2half(dy * eo));
    unsigned hz = __half_as_ushort(__float2half(dz * eo));
    return (unsigned long long)lid
         | ((unsigned long long)hx << 11)
         | ((unsigned long long)hy << 27)
         | ((unsigned long long)hz << 43);
}

// ---- split path: streaming compute; batched gathers; per-block hist -> histG
__global__ __launch_bounds__(TPB1, 6) void compute_kernel(
        const uint2* __restrict__ xh,
        const int* __restrict__ ei,
        const float* __restrict__ Wp1, const float* __restrict__ bp1,
        const float* __restrict__ Wp2, const float* __restrict__ consts,
        uint2* __restrict__ rec_raw, unsigned* __restrict__ histG, int E, int K) {
    __shared__ unsigned hist[4][KMAX];
    __shared__ float sW1[HDIM], sb1[HDIM], sW2[HDIM];
    const float C = consts[0];
    const bool slow = (consts[1] != 0.f);
    if (slow) {
        for (int k = threadIdx.x; k < HDIM; k += TPB1) {
            sW1[k] = Wp1[k]; sb1[k] = bp1[k]; sW2[k] = Wp2[k];
        }
    }
    int w = threadIdx.x >> 6;
    for (int k = threadIdx.x; k < 4 * KMAX; k += TPB1) ((unsigned*)hist)[k] = 0;
    __syncthreads();

    const size_t base = (size_t)blockIdx.x * EPB;
    const unsigned t = threadIdx.x;
    if (base + EPB <= (size_t)E && (E & 3) == 0) {
        const int4* pr = (const int4*)(ei + base);
        const int4* pc = (const int4*)(ei + (size_t)E + base);
        int4* po = (int4*)(rec_raw + base);
        #pragma unroll
        for (int i = 0; i < PERT / 4; i++) {
            unsigned idx = t + i * TPB1;
            int4 rv = pr[idx];
            int4 cv = pc[idx];
            int rr[4] = {rv.x, rv.y, rv.z, rv.w};
            int cc[4] = {cv.x, cv.y, cv.z, cv.w};
            // batch all 8 gathers: 8 loads in flight, single wait
            uint2 ga[4], gb[4];
            #pragma unroll
            for (int q = 0; q < 4; q++) { ga[q] = xh[rr[q]]; gb[q] = xh[cc[q]]; }
            uint2 outr[4];
            #pragma unroll
            for (int q = 0; q < 4; q++) {
                float ax = __half2float(__ushort_as_half((unsigned short)(ga[q].x & 0xFFFF)));
                float ay = __half2float(__ushort_as_half((unsigned short)(ga[q].x >> 16)));
                float az = __half2float(__ushort_as_half((unsigned short)(ga[q].y & 0xFFFF)));
                float bx = __half2float(__ushort_as_half((unsigned short)(gb[q].x & 0xFFFF)));
                float by = __half2float(__ushort_as_half((unsigned short)(gb[q].x >> 16)));
                float bz = __half2float(__ushort_as_half((unsigned short)(gb[q].y & 0xFFFF)));
                float dx = ax - bx, dy = ay - by, dz = az - bz;
                float rad = sqrtf(dx*dx + dy*dy + dz*dz);
                float eo = edge_eo(rad, C, slow, sW1, sb1, sW2);
                int r = rr[q];
                unsigned long long u = pack_rec(dx, dy, dz, eo, (unsigned)r & (RANGE - 1));
                outr[q] = make_uint2((unsigned)u, (unsigned)(u >> 32));
                atomicAdd(&hist[w][((unsigned)r) >> RSH], 1u);
            }
            po[2*idx]     = make_int4((int)outr[0].x, (int)outr[0].y, (int)outr[1].x, (int)outr[1].y);
            po[2*idx + 1] = make_int4((int)outr[2].x, (int)outr[2].y, (int)outr[3].x, (int)outr[3].y);
        }
    } else {
        for (int i = 0; i < PERT; i++) {
            size_t e = base + (size_t)i * TPB1 + t;
            if (e < (size_t)E) {
                int r = ei[e];
                int c = ei[(size_t)E + e];
                uint2 ga = xh[r], gb = xh[c];
                float ax = __half2float(__ushort_as_half((unsigned short)(ga.x & 0xFFFF)));
                float ay = __half2float(__ushort_as_half((unsigned short)(ga.x >> 16)));
                float az = __half2float(__ushort_as_half((unsigned short)(ga.y & 0xFFFF)));
                float bx = __half2float(__ushort_as_half((unsigned short)(gb.x & 0xFFFF)));
                float by = __half2float(__ushort_as_half((unsigned short)(gb.x >> 16)));
                float bz = __half2float(__ushort_as_half((unsigned short)(gb.y & 0xFFFF)));
                float dx = ax - bx, dy = ay - by, dz = az - bz;
                float rad = sqrtf(dx*dx + dy*dy + dz*dz);
                float eo = edge_eo(rad, C, slow, sW1, sb1, sW2);
                unsigned long long u = pack_rec(dx, dy, dz, eo, (unsigned)r & (RANGE - 1));
                rec_raw[e] = make_uint2((unsigned)u, (unsigned)(u >> 32));
                atomicAdd(&hist[w][((unsigned)r) >> RSH], 1u);
            }
        }
    }
    __syncthreads();
    for (int k = threadIdx.x; k < K; k += TPB1)
        histG[(size_t)blockIdx.x * K + k] = hist[0][k] + hist[1][k] + hist[2][k] + hist[3][k];
}

// one block per bucket b: exclusive prefix over blocks of histG[.][b] (in place) + totals[b]
__global__ __launch_bounds__(256) void colscan_kernel(unsigned* __restrict__ histG,
                                                      unsigned* __restrict__ totals,
                                                      int nblk, int K) {
    __shared__ unsigned pa[256], pb[256];
    const int b = blockIdx.x;
    const int t = threadIdx.x;
    const int chunk = (nblk + 255) / 256;
    const int r0 = t * chunk;
    unsigned s = 0;
    for (int i = 0; i < chunk; i++) {
        int r = r0 + i;
        if (r < nblk) s += histG[(size_t)r * K + b];
    }
    pa[t] = s;
    __syncthreads();
    unsigned* src = pa; unsigned* dst = pb;
    for (int off = 1; off < 256; off <<= 1) {
        unsigned v = src[t];
        if (t >= off) v += src[t - off];
        dst[t] = v;
        __syncthreads();
        unsigned* tmp = src; src = dst; dst = tmp;
    }
    unsigned excl = (t > 0) ? src[t - 1] : 0u;
    if (t == 255) totals[b] = src[255];
    unsigned run = excl;
    for (int i = 0; i < chunk; i++) {
        int r = r0 + i;
        if (r < nblk) {
            size_t a = (size_t)r * K + b;
            unsigned v = histG[a];
            histG[a] = run;
            run += v;
        }
    }
}

__global__ void base_scan_kernel(const unsigned* __restrict__ totals,
                                 unsigned* __restrict__ base, int K) {
    if (threadIdx.x == 0) {
        unsigned acc = 0;
        for (int k = 0; k < K; k++) { base[k] = acc; acc += totals[k]; }
        base[K] = acc;
    }
}

// ---- split path: sort only — R9-verified scatter, gstart from precomputed offsets
__global__ __launch_bounds__(TPB1) void sort_kernel(
        const int* __restrict__ ei, const uint2* __restrict__ rec_raw,
        const unsigned* __restrict__ histG, const unsigned* __restrict__ basep,
        uint2* __restrict__ recs, int E, int K) {
    __shared__ uint2 stage[EPB];                 // 16 KB
    __shared__ unsigned char bucket_of[EPB];     // 2 KB
    __shared__ unsigned hist[KMAX];
    __shared__ unsigned scanv[KMAX + 1];
    __shared__ unsigned gstart[KMAX];
    for (int k = threadIdx.x; k < K; k += TPB1) hist[k] = 0;
    __syncthreads();

    const size_t base = (size_t)blockIdx.x * EPB;
    uint2 rc[PERT];
    unsigned bk[PERT];
    #pragma unroll
    for (int i = 0; i < PERT; i++) {
        size_t e = base + (size_t)i * TPB1 + threadIdx.x;
        bk[i] = 0xFFFFFFFFu;
        if (e < (size_t)E) {
            rc[i] = rec_raw[e];
            unsigned b_ = ((unsigned)ei[e]) >> RSH;
            bk[i] = b_;
            atomicAdd(&hist[b_], 1u);
        }
    }
    __syncthreads();
    if (threadIdx.x == 0) {
        unsigned a = 0;
        for (int k = 0; k < K; k++) { scanv[k] = a; a += hist[k]; }
        scanv[K] = a;
    }
    __syncthreads();
    if (threadIdx.x < (unsigned)K)
        gstart[threadIdx.x] = basep[threadIdx.x]
                            + histG[(size_t)blockIdx.x * K + threadIdx.x];
    for (int k = threadIdx.x; k < K; k += TPB1) hist[k] = scanv[k];  // running cursors
    __syncthreads();
    #pragma unroll
    for (int i = 0; i < PERT; i++) {
        if (bk[i] != 0xFFFFFFFFu) {
            unsigned slot = atomicAdd(&hist[bk[i]], 1u);
            stage[slot] = rc[i];
            bucket_of[slot] = (unsigned char)bk[i];
        }
    }
    __syncthreads();
    unsigned total = scanv[K];
    for (unsigned j = threadIdx.x; j < total; j += TPB1) {
        unsigned b_ = bucket_of[j];
        recs[(size_t)gstart[b_] + (j - scanv[b_])] = stage[j];
    }
}

// ---- fused fallback (R7-verified, with cursor atomics) ----
__global__ __launch_bounds__(TPB1) void count_kernel(const int* __restrict__ ei,
                                                     unsigned* __restrict__ cnts,
                                                     int E, int K) {
    __shared__ unsigned hist[4][KMAX];
    int w = threadIdx.x >> 6;
    for (int k = threadIdx.x; k < 4 * KMAX; k += TPB1) ((unsigned*)hist)[k] = 0;
    __syncthreads();
    int base = blockIdx.x * EPB;
    #pragma unroll
    for (int i = 0; i < PERT; i++) {
        int e = base + i * TPB1 + threadIdx.x;
        if (e < E) atomicAdd(&hist[w][((unsigned)ei[e]) >> RSH], 1u);
    }
    __syncthreads();
    for (int k = threadIdx.x; k < K; k += TPB1) {
        unsigned t = hist[0][k] + hist[1][k] + hist[2][k] + hist[3][k];
        if (t) atomicAdd(&cnts[k], t);
    }
}

__global__ void scan_kernel(const unsigned* __restrict__ cnts,
                            unsigned* __restrict__ base,
                            unsigned* __restrict__ cursor, int K) {
    if (threadIdx.x == 0) {
        unsigned acc = 0;
        for (int k = 0; k < K; k++) { base[k] = acc; cursor[k] = acc; acc += cnts[k]; }
        base[K] = acc;
    }
}

__global__ __launch_bounds__(TPB1) void bin_kernel(
        const float* __restrict__ x, const float4* __restrict__ x4, int use4,
        const int* __restrict__ ei,
        const float* __restrict__ Wp1, const float* __restrict__ bp1,
        const float* __restrict__ Wp2, const float* __restrict__ consts,
        unsigned* __restrict__ cursor, uint2* __restrict__ recs, int E, int K) {
    __shared__ uint2 stage[EPB];
    __shared__ unsigned char bucket_of[EPB];
    __shared__ unsigned hist[KMAX];
    __shared__ unsigned scanv[KMAX + 1];
    __shared__ unsigned gstart[KMAX];
    __shared__ float sW1[HDIM], sb1[HDIM], sW2[HDIM];
    const float C = consts[0];
    const bool slow = (consts[1] != 0.f);
    if (slow) {
        for (int k = threadIdx.x; k < HDIM; k += TPB1) {
            sW1[k] = Wp1[k]; sb1[k] = bp1[k]; sW2[k] = Wp2[k];
        }
    }
    for (int k = threadIdx.x; k < K; k += TPB1) hist[k] = 0;
    __syncthreads();

    int base = blockIdx.x * EPB;
    uint2 rc[PERT];
    unsigned bk[PERT];
    #pragma unroll
    for (int i = 0; i < PERT; i++) {
        int e = base + i * TPB1 + threadIdx.x;
        bk[i] = 0xFFFFFFFFu;
        if (e < E) {
            int r = ei[e];
            int c = ei[(size_t)E + e];
            float dx, dy, dz;
            if (use4) {
                float4 a = x4[r], b = x4[c];
                dx = a.x - b.x; dy = a.y - b.y; dz = a.z - b.z;
            } else {
                dx = x[3*r]   - x[3*c];
                dy = x[3*r+1] - x[3*c+1];
                dz = x[3*r+2] - x[3*c+2];
            }
            float rad = sqrtf(dx*dx + dy*dy + dz*dz);
            float eo = edge_eo(rad, C, slow, sW1, sb1, sW2);
            unsigned long long u = pack_rec(dx, dy, dz, eo, (unsigned)r & (RANGE - 1));
            rc[i] = make_uint2((unsigned)u, (unsigned)(u >> 32));
            bk[i] = (unsigned)r >> RSH;
            atomicAdd(&hist[bk[i]], 1u);
        }
    }
    __syncthreads();
    if (threadIdx.x == 0) {
        unsigned a = 0;
        for (int k = 0; k < K; k++) { scanv[k] = a; a += hist[k]; }
        scanv[K] = a;
    }
    __syncthreads();
    if (threadIdx.x < (unsigned)K) {
        unsigned c_ = scanv[threadIdx.x + 1] - scanv[threadIdx.x];
        gstart[threadIdx.x] = c_ ? atomicAdd(&cursor[threadIdx.x], c_) : 0u;
    }
    for (int k = threadIdx.x; k < K; k += TPB1) hist[k] = scanv[k];
    __syncthreads();
    #pragma unroll
    for (int i = 0; i < PERT; i++) {
        if (bk[i] != 0xFFFFFFFFu) {
            unsigned slot = atomicAdd(&hist[bk[i]], 1u);
            stage[slot] = rc[i];
            bucket_of[slot] = (unsigned char)bk[i];
        }
    }
    __syncthreads();
    unsigned total = scanv[K];
    for (unsigned j = threadIdx.x; j < total; j += TPB1) {
        unsigned b_ = bucket_of[j];
        recs[(size_t)gstart[b_] + (j - scanv[b_])] = stage[j];
    }
}

__device__ __forceinline__ void proc_rec(uint2 r, unsigned (*acc)[RANGE]) {
    unsigned long long u = ((unsigned long long)r.y << 32) | r.x;
    unsigned lid = (unsigned)(u & (RANGE - 1));
    float mx = __half2float(__ushort_as_half((unsigned short)((u >> 11) & 0xFFFF)));
    float my = __half2float(__ushort_as_half((unsigned short)((u >> 27) & 0xFFFF)));
    float mz = __half2float(__ushort_as_half((unsigned short)((u >> 43) & 0xFFFF)));
    // fixed-point u32 atomics: fast int LDS path (round-5 verified)
    atomicAdd(&acc[0][lid], (unsigned)(int)__float2int_rn(mx * FIXS));
    atomicAdd(&acc[1][lid], (unsigned)(int)__float2int_rn(my * FIXS));
    atomicAdd(&acc[2][lid], (unsigned)(int)__float2int_rn(mz * FIXS));
    atomicAdd(&acc[3][lid], 1u);
}

__global__ __launch_bounds__(256) void reduce_kernel(
        const uint2* __restrict__ recs, const unsigned* __restrict__ base,
        float4* __restrict__ slices, int N, int K) {
    __shared__ unsigned acc[4][RANGE];
    int b = blockIdx.x / NSLICE;
    int s = blockIdx.x % NSLICE;
    for (int i = threadIdx.x; i < RANGE; i += 256) {
        acc[0][i] = 0u; acc[1][i] = 0u; acc[2][i] = 0u; acc[3][i] = 0u;
    }
    __syncthreads();
    unsigned lo = base[b], hi = base[b + 1];
    unsigned cnt = hi - lo;
    unsigned per = (cnt + NSLICE - 1) / NSLICE;
    unsigned st = lo + (unsigned)s * per;
    unsigned en = st + per; if (en > hi) en = hi;
    unsigned j = st + threadIdx.x;
    if (st < hi) {
        while (j + 256 < en) {
            uint2 r0 = recs[j];
            uint2 r1 = recs[j + 256];
            proc_rec(r0, acc);
            proc_rec(r1, acc);
            j += 512;
        }
        while (j < en) { proc_rec(recs[j], acc); j += 256; }
    }
    __syncthreads();
    int nbase = b * RANGE;
    for (int i = threadIdx.x; i < RANGE; i += 256) {
        int node = nbase + i;
        if (node < N)
            slices[(size_t)s * N + node] =
                make_float4((float)(int)acc[0][i] * INVFIXS,
                            (float)(int)acc[1][i] * INVFIXS,
                            (float)(int)acc[2][i] * INVFIXS,
                            (float)acc[3][i]);
    }
}

__global__ void node_kernel(const float* __restrict__ x, const float* __restrict__ vel_norm,
                            const float* __restrict__ vel,
                            const float* __restrict__ W1, const float* __restrict__ b1,
                            const float* __restrict__ W2, const float* __restrict__ b2,
                            const float4* __restrict__ slices,
                            float* __restrict__ out, int N, int S) {
    __shared__ float sW1[HDIM], sb1[HDIM], sW2[HDIM];
    for (int k = threadIdx.x; k < HDIM; k += blockDim.x) {
        sW1[k] = W1[k]; sb1[k] = b1[k]; sW2[k] = W2[k];
    }
    __syncthreads();
    int i = blockIdx.x * blockDim.x + threadIdx.x;
    if (i >= N) return;
    float sx = 0.f, sy = 0.f, sz = 0.f, sc = 0.f;
    for (int s = 0; s < S; s++) {
        float4 v = slices[(size_t)s * N + i];
        sx += v.x; sy += v.y; sz += v.z; sc += v.w;
    }
    float vn = vel_norm[i];
    float a = b2[0];
    #pragma unroll
    for (int k = 0; k < HDIM; k++) {
        float h = fmaf(vn, sW1[k], sb1[k]);
        h = (h > 0.f) ? h : LEAKY * h;
        a = fmaf(sW2[k], h, a);
    }
    float inv = 1.0f / fmaxf(sc, 1.0f);
    out[3*i]     = x[3*i]     + sx * inv + vel[3*i]     * a;
    out[3*i + 1] = x[3*i + 1] + sy * inv + vel[3*i + 1] * a;
    out[3*i + 2] = x[3*i + 2] + sz * inv + vel[3*i + 2] * a;
}

// final fallback: plain device-scope atomics
__global__ void edge_atomic_kernel(const float* __restrict__ x, const int* __restrict__ ei,
                                   const float* __restrict__ Wp1, const float* __restrict__ bp1,
                                   const float* __restrict__ Wp2, const float* __restrict__ consts,
                                   float* __restrict__ acc, int E) {
    __shared__ float sW1[HDIM], sb1[HDIM], sW2[HDIM];
    const float C = consts[0];
    const bool slow = (consts[1] != 0.f);
    if (slow) {
        for (int k = threadIdx.x; k < HDIM; k += blockDim.x) {
            sW1[k] = Wp1[k]; sb1[k] = bp1[k]; sW2[k] = Wp2[k];
        }
        __syncthreads();
    }
    int e = blockIdx.x * blockDim.x + threadIdx.x;
    if (e >= E) return;
    int r = ei[e];
    int c = ei[E + e];
    float dx = x[3*r] - x[3*c];
    float dy = x[3*r+1] - x[3*c+1];
    float dz = x[3*r+2] - x[3*c+2];
    float rad = sqrtf(dx*dx + dy*dy + dz*dz);
    float eo = edge_eo(rad, C, slow, sW1, sb1, sW2);
    float* basep = acc + ((size_t)r << 2);
    atomicAdd(basep + 0, dx * eo);
    atomicAdd(basep + 1, dy * eo);
    atomicAdd(basep + 2, dz * eo);
    atomicAdd(basep + 3, 1.f);
}

extern "C" void kernel_launch(void* const* d_in, const int* in_sizes, int n_in,
                              void* d_out, int out_size, void* d_ws, size_t ws_size,
                              hipStream_t stream) {
    const float* x        = (const float*)d_in[0];
    const float* vel_norm = (const float*)d_in[1];
    const float* vel      = (const float*)d_in[2];
    const int*   ei       = (const int*)  d_in[3];
    const float* W1       = (const float*)d_in[4];
    const float* b1       = (const float*)d_in[5];
    const float* W2       = (const float*)d_in[6];
    const float* b2       = (const float*)d_in[7];
    const float* Wp1      = (const float*)d_in[8];
    const float* bp1      = (const float*)d_in[9];
    const float* Wp2      = (const float*)d_in[10];

    const int N = in_sizes[0] / 3;
    const int E = in_sizes[3] / 2;
    const int K = (N + RANGE - 1) / RANGE;
    const int nblk = (E + EPB - 1) / EPB;

    size_t rec_bytes   = (size_t)E * sizeof(uint2);
    size_t slice_bytes = (size_t)NSLICE * N * sizeof(float4);
    size_t x4_bytes    = (size_t)N * sizeof(float4);
    size_t histG_bytes = (size_t)nblk * K * sizeof(unsigned);

    // split layout: [recs][raw | slices overlay][xh][histG][totals][base][consts]
    size_t sp_raw   = rec_bytes;
    size_t sp_x4    = sp_raw + (rec_bytes > slice_bytes ? rec_bytes : slice_bytes);
    size_t sp_hist  = sp_x4 + x4_bytes;
    size_t sp_tot   = sp_hist + histG_bytes;
    size_t sp_base  = sp_tot + (size_t)K * sizeof(unsigned);
    size_t sp_const = (sp_base + (size_t)(K + 1) * sizeof(unsigned) + 15) & ~(size_t)15;
    size_t need_split = sp_const + 32;

    // fused layout: [slices][recs][x4][small: cnts|base|cursor|consts]
    size_t small_bytes = (size_t)(KMAX + (KMAX + 1) + KMAX) * sizeof(unsigned) + 32;
    size_t fu_recs  = slice_bytes;
    size_t fu_x4    = fu_recs + rec_bytes;
    size_t fu_small = fu_x4 + x4_bytes;
    size_t need_fused = fu_small + small_bytes;

    if (K <= KMAX && ws_size >= need_split) {
        uint2*    recs   = (uint2*)   d_ws;
        uint2*    raw    = (uint2*)   ((char*)d_ws + sp_raw);
        float4*   slices = (float4*)  ((char*)d_ws + sp_raw);   // overlay: raw dead after sort
        uint2*    xh     = (uint2*)   ((char*)d_ws + sp_x4);
        unsigned* histG  = (unsigned*)((char*)d_ws + sp_hist);
        unsigned* totals = (unsigned*)((char*)d_ws + sp_tot);
        unsigned* basep  = (unsigned*)((char*)d_ws + sp_base);
        float*    consts = (float*)   ((char*)d_ws + sp_const);

        precompute_kernel<<<1, 64, 0, stream>>>(Wp1, bp1, Wp2, consts);
        repack_h_kernel<<<(N + 255) / 256, 256, 0, stream>>>(x, xh, N);
        compute_kernel<<<nblk, TPB1, 0, stream>>>(xh, ei, Wp1, bp1, Wp2, consts,
                                                  raw, histG, E, K);
        colscan_kernel<<<K, 256, 0, stream>>>(histG, totals, nblk, K);
        base_scan_kernel<<<1, 64, 0, stream>>>(totals, basep, K);
        sort_kernel<<<nblk, TPB1, 0, stream>>>(ei, raw, histG, basep, recs, E, K);
        reduce_kernel<<<K * NSLICE, 256, 0, stream>>>(recs, basep, slices, N, K);
        node_kernel<<<(N + 255) / 256, 256, 0, stream>>>(x, vel_norm, vel, W1, b1, W2, b2,
                                                         slices, (float*)d_out, N, NSLICE);
    } else if (K <= KMAX && ws_size >= need_fused) {
        float4*   slices = (float4*)  d_ws;
        uint2*    recs   = (uint2*)   ((char*)d_ws + fu_recs);
        float4*   x4     = (float4*)  ((char*)d_ws + fu_x4);
        unsigned* cnts   = (unsigned*)((char*)d_ws + fu_small);
        unsigned* basep  = cnts + KMAX;
        unsigned* cursor = basep + KMAX + 1;
        float*    consts = (float*)(cursor + KMAX);

        hipMemsetAsync(cnts, 0, small_bytes, stream);
        precompute_kernel<<<1, 64, 0, stream>>>(Wp1, bp1, Wp2, consts);
        repack_kernel<<<(N + 255) / 256, 256, 0, stream>>>(x, x4, N);
        count_kernel<<<nblk, TPB1, 0, stream>>>(ei, cnts, E, K);
        scan_kernel<<<1, 64, 0, stream>>>(cnts, basep, cursor, K);
        bin_kernel<<<nblk, TPB1, 0, stream>>>(x, x4, 1, ei, Wp1, bp1, Wp2, consts,
                                              cursor, recs, E, K);
        reduce_kernel<<<K * NSLICE, 256, 0, stream>>>(recs, basep, slices, N, K);
        node_kernel<<<(N + 255) / 256, 256, 0, stream>>>(x, vel_norm, vel, W1, b1, W2, b2,
                                                         slices, (float*)d_out, N, NSLICE);
    } else {
        float* acc    = (float*)d_ws;
        float* consts = (float*)((char*)d_ws + (size_t)N * sizeof(float4));
        hipMemsetAsync(d_ws, 0, (size_t)N * sizeof(float4) + 32, stream);
        precompute_kernel<<<1, 64, 0, stream>>>(Wp1, bp1, Wp2, consts);
        edge_atomic_kernel<<<(E + 255) / 256, 256, 0, stream>>>(x, ei, Wp1, bp1, Wp2,
                                                                consts, acc, E);
        node_kernel<<<(N + 255) / 256, 256, 0, stream>>>(x, vel_norm, vel, W1, b1, W2, b2,
                                                         (const float4*)acc, (float*)d_out, N, 1);
    }
}

// Round 11
// 223.562 us; speedup vs baseline: 1.2926x; 1.2926x over previous
//
#include <hip/hip_runtime.h>
#include <hip/hip_fp16.h>
#include <math.h>

#define LEAKY 0.2f
#define HDIM 64
#define EPB 2048            // edges per block (compute, sort, count)
#define TPB1 256
#define PERT (EPB / TPB1)   // 8 edges per thread
#define RANGE 1024          // nodes per bucket
#define RSH 10
#define KMAX 128
#define NSLICE 12
#define FIXS 4194304.0f     // 2^22 fixed-point scale
#define INVFIXS (1.0f / 4194304.0f)

// record: bits [0,11) lid, [11,27) f16 mx, [27,43) f16 my, [43,59) f16 mz

__global__ void precompute_kernel(const float* __restrict__ Wp1,
                                  const float* __restrict__ bp1,
                                  const float* __restrict__ Wp2,
                                  float* __restrict__ consts) {
    int k = threadIdx.x;  // 64 threads == HDIM == one wave
    float w1 = Wp1[k];
    float slope = (w1 >= 0.f) ? 1.f : LEAKY;
    float c = Wp2[k] * w1 * slope;
    float bnz = (bp1[k] != 0.f) ? 1.f : 0.f;
    #pragma unroll
    for (int off = 32; off > 0; off >>= 1) {
        c += __shfl_down(c, off, 64);
        bnz += __shfl_down(bnz, off, 64);
    }
    if (k == 0) { consts[0] = c; consts[1] = bnz; }
}

// tanh(v) = 1 - 2/(exp2(v*2*log2e)+1); exact saturation, ~1e-6 rel err (R10-verified)
__device__ __forceinline__ float fast_tanh(float v) {
    float e = __builtin_amdgcn_exp2f(v * 2.88539008178f);
    return 1.0f - 2.0f * __builtin_amdgcn_rcpf(e + 1.0f);
}

__device__ __forceinline__ float edge_eo(float rad, float C, bool slow,
                                         const float* sW1, const float* sb1,
                                         const float* sW2) {
    if (!slow) return fast_tanh(C * rad);  // bp1==0, rad>=0: MLP collapses to linear
    float a = 0.f;
    #pragma unroll
    for (int k = 0; k < HDIM; k++) {
        float h = fmaf(rad, sW1[k], sb1[k]);
        h = (h > 0.f) ? h : LEAKY * h;
        a = fmaf(sW2[k], h, a);
    }
    return fast_tanh(a);
}

__global__ void repack_kernel(const float* __restrict__ x, float4* __restrict__ x4, int N) {
    int i = blockIdx.x * blockDim.x + threadIdx.x;
    if (i < N) x4[i] = make_float4(x[3*i], x[3*i+1], x[3*i+2], 0.f);
}

// half-packed coords: 8 B/node -> 8 nodes per 64B line
__global__ void repack_h_kernel(const float* __restrict__ x, uint2* __restrict__ xh, int N) {
    int i = blockIdx.x * blockDim.x + threadIdx.x;
    if (i < N) {
        unsigned hx = __half_as_ushort(__float2half(x[3*i]));
        unsigned hy = __half_as_ushort(__float2half(x[3*i+1]));
        unsigned hz = __half_as_ushort(__float2half(x[3*i+2]));
        xh[i] = make_uint2((hy << 16) | hx, hz);
    }
}

__device__ __forceinline__ unsigned long long pack_rec(float dx, float dy, float dz,
                                                       float eo, unsigned lid) {
    unsigned hx = __half_as_ushort(__float2half(dx * eo));
    unsigned hy = __half_as_ushort(__float2half(dy * eo));
    unsigned hz = __half_as_ushort(__float2half(dz * eo));
    return (unsigned long long)lid
         | ((unsigned long long)hx << 11)
         | ((unsigned long long)hy << 27)
         | ((unsigned long long)hz << 43);
}

__device__ __forceinline__ uint2 make_record(uint2 ga, uint2 gb, int r,
                                             float C, bool slow,
                                             const float* sW1, const float* sb1,
                                             const float* sW2) {
    float ax = __half2float(__ushort_as_half((unsigned short)(ga.x & 0xFFFF)));
    float ay = __half2float(__ushort_as_half((unsigned short)(ga.x >> 16)));
    float az = __half2float(__ushort_as_half((unsigned short)(ga.y & 0xFFFF)));
    float bx = __half2float(__ushort_as_half((unsigned short)(gb.x & 0xFFFF)));
    float by = __half2float(__ushort_as_half((unsigned short)(gb.x >> 16)));
    float bz = __half2float(__ushort_as_half((unsigned short)(gb.y & 0xFFFF)));
    float dx = ax - bx, dy = ay - by, dz = az - bz;
    float rad = sqrtf(dx*dx + dy*dy + dz*dz);
    float eo = edge_eo(rad, C, slow, sW1, sb1, sW2);
    unsigned long long u = pack_rec(dx, dy, dz, eo, (unsigned)r & (RANGE - 1));
    return make_uint2((unsigned)u, (unsigned)(u >> 32));
}

// ---- split path: streaming compute; scalar batched gathers; DENSE permuted stores
// Per-block layout (fast path): records for local edges j=4*idx+q are stored as
// uint2 slot  ((q>=2)?1024:0) + 2*idx + (q&1)   — each int4 store is stride-16 dense.
__global__ __launch_bounds__(TPB1) void compute_kernel(
        const uint2* __restrict__ xh,
        const int* __restrict__ ei,
        const float* __restrict__ Wp1, const float* __restrict__ bp1,
        const float* __restrict__ Wp2, const float* __restrict__ consts,
        uint2* __restrict__ rec_raw, unsigned* __restrict__ histG, int E, int K) {
    __shared__ unsigned hist[4][KMAX];
    __shared__ float sW1[HDIM], sb1[HDIM], sW2[HDIM];
    const float C = consts[0];
    const bool slow = (consts[1] != 0.f);
    if (slow) {
        for (int k = threadIdx.x; k < HDIM; k += TPB1) {
            sW1[k] = Wp1[k]; sb1[k] = bp1[k]; sW2[k] = Wp2[k];
        }
    }
    int w = threadIdx.x >> 6;
    for (int k = threadIdx.x; k < 4 * KMAX; k += TPB1) ((unsigned*)hist)[k] = 0;
    __syncthreads();

    const size_t base = (size_t)blockIdx.x * EPB;
    const unsigned t = threadIdx.x;
    if (base + EPB <= (size_t)E && (E & 3) == 0) {
        const int4* pr = (const int4*)(ei + base);
        const int4* pc = (const int4*)(ei + (size_t)E + base);
        int4* po = (int4*)(rec_raw + base);
        const int HALFI4 = EPB / 4;   // 512 int4 slots per half-plane
        #pragma unroll
        for (int i = 0; i < PERT / 4; i++) {
            unsigned idx = t + i * TPB1;
            int4 rv = pr[idx];
            int4 cv = pc[idx];
            // batched gathers as scalars (no indexed arrays -> no spill trigger)
            uint2 ga0 = xh[rv.x], gb0 = xh[cv.x];
            uint2 ga1 = xh[rv.y], gb1 = xh[cv.y];
            uint2 ga2 = xh[rv.z], gb2 = xh[cv.z];
            uint2 ga3 = xh[rv.w], gb3 = xh[cv.w];
            uint2 r0 = make_record(ga0, gb0, rv.x, C, slow, sW1, sb1, sW2);
            uint2 r1 = make_record(ga1, gb1, rv.y, C, slow, sW1, sb1, sW2);
            uint2 r2 = make_record(ga2, gb2, rv.z, C, slow, sW1, sb1, sW2);
            uint2 r3 = make_record(ga3, gb3, rv.w, C, slow, sW1, sb1, sW2);
            atomicAdd(&hist[w][((unsigned)rv.x) >> RSH], 1u);
            atomicAdd(&hist[w][((unsigned)rv.y) >> RSH], 1u);
            atomicAdd(&hist[w][((unsigned)rv.z) >> RSH], 1u);
            atomicAdd(&hist[w][((unsigned)rv.w) >> RSH], 1u);
            // DENSE stores: stride-16 within each instruction
            po[idx]          = make_int4((int)r0.x, (int)r0.y, (int)r1.x, (int)r1.y);
            po[HALFI4 + idx] = make_int4((int)r2.x, (int)r2.y, (int)r3.x, (int)r3.y);
        }
    } else {
        for (int i = 0; i < PERT; i++) {
            size_t e = base + (size_t)i * TPB1 + t;
            if (e < (size_t)E) {
                int r = ei[e];
                int c = ei[(size_t)E + e];
                uint2 ga = xh[r], gb = xh[c];
                uint2 rec = make_record(ga, gb, r, C, slow, sW1, sb1, sW2);
                rec_raw[e] = rec;   // identity layout on tail blocks
                atomicAdd(&hist[w][((unsigned)r) >> RSH], 1u);
            }
        }
    }
    __syncthreads();
    for (int k = threadIdx.x; k < K; k += TPB1)
        histG[(size_t)blockIdx.x * K + k] = hist[0][k] + hist[1][k] + hist[2][k] + hist[3][k];
}

// one block per bucket b: exclusive prefix over blocks of histG[.][b] (in place) + totals[b]
__global__ __launch_bounds__(256) void colscan_kernel(unsigned* __restrict__ histG,
                                                      unsigned* __restrict__ totals,
                                                      int nblk, int K) {
    __shared__ unsigned pa[256], pb[256];
    const int b = blockIdx.x;
    const int t = threadIdx.x;
    const int chunk = (nblk + 255) / 256;
    const int r0 = t * chunk;
    unsigned s = 0;
    for (int i = 0; i < chunk; i++) {
        int r = r0 + i;
        if (r < nblk) s += histG[(size_t)r * K + b];
    }
    pa[t] = s;
    __syncthreads();
    unsigned* src = pa; unsigned* dst = pb;
    for (int off = 1; off < 256; off <<= 1) {
        unsigned v = src[t];
        if (t >= off) v += src[t - off];
        dst[t] = v;
        __syncthreads();
        unsigned* tmp = src; src = dst; dst = tmp;
    }
    unsigned excl = (t > 0) ? src[t - 1] : 0u;
    if (t == 255) totals[b] = src[255];
    unsigned run = excl;
    for (int i = 0; i < chunk; i++) {
        int r = r0 + i;
        if (r < nblk) {
            size_t a = (size_t)r * K + b;
            unsigned v = histG[a];
            histG[a] = run;
            run += v;
        }
    }
}

__global__ void base_scan_kernel(const unsigned* __restrict__ totals,
                                 unsigned* __restrict__ base, int K) {
    if (threadIdx.x == 0) {
        unsigned acc = 0;
        for (int k = 0; k < K; k++) { base[k] = acc; acc += totals[k]; }
        base[K] = acc;
    }
}

// ---- split path: sort only — R9-verified scatter; reads permuted raw layout
__global__ __launch_bounds__(TPB1) void sort_kernel(
        const int* __restrict__ ei, const uint2* __restrict__ rec_raw,
        const unsigned* __restrict__ histG, const unsigned* __restrict__ basep,
        uint2* __restrict__ recs, int E, int K) {
    __shared__ uint2 stage[EPB];                 // 16 KB
    __shared__ unsigned char bucket_of[EPB];     // 2 KB
    __shared__ unsigned hist[KMAX];
    __shared__ unsigned scanv[KMAX + 1];
    __shared__ unsigned gstart[KMAX];
    for (int k = threadIdx.x; k < K; k += TPB1) hist[k] = 0;
    __syncthreads();

    const size_t base = (size_t)blockIdx.x * EPB;
    const bool perm = (base + EPB <= (size_t)E) && ((E & 3) == 0);
    uint2 rc[PERT];
    unsigned bk[PERT];
    #pragma unroll
    for (int i = 0; i < PERT; i++) {
        size_t e = base + (size_t)i * TPB1 + threadIdx.x;
        bk[i] = 0xFFFFFFFFu;
        if (e < (size_t)E) {
            size_t pos = e;
            if (perm) {
                unsigned j = (unsigned)(e - base);
                pos = base + ((size_t)((j >> 1) & 1u) * (EPB / 2))
                           + ((j >> 2) << 1) + (j & 1u);
            }
            rc[i] = rec_raw[pos];
            unsigned b_ = ((unsigned)ei[e]) >> RSH;
            bk[i] = b_;
            atomicAdd(&hist[b_], 1u);
        }
    }
    __syncthreads();
    if (threadIdx.x == 0) {
        unsigned a = 0;
        for (int k = 0; k < K; k++) { scanv[k] = a; a += hist[k]; }
        scanv[K] = a;
    }
    __syncthreads();
    if (threadIdx.x < (unsigned)K)
        gstart[threadIdx.x] = basep[threadIdx.x]
                            + histG[(size_t)blockIdx.x * K + threadIdx.x];
    for (int k = threadIdx.x; k < K; k += TPB1) hist[k] = scanv[k];  // running cursors
    __syncthreads();
    #pragma unroll
    for (int i = 0; i < PERT; i++) {
        if (bk[i] != 0xFFFFFFFFu) {
            unsigned slot = atomicAdd(&hist[bk[i]], 1u);
            stage[slot] = rc[i];
            bucket_of[slot] = (unsigned char)bk[i];
        }
    }
    __syncthreads();
    unsigned total = scanv[K];
    for (unsigned j = threadIdx.x; j < total; j += TPB1) {
        unsigned b_ = bucket_of[j];
        recs[(size_t)gstart[b_] + (j - scanv[b_])] = stage[j];
    }
}

// ---- fused fallback (R7-verified, with cursor atomics) ----
__global__ __launch_bounds__(TPB1) void count_kernel(const int* __restrict__ ei,
                                                     unsigned* __restrict__ cnts,
                                                     int E, int K) {
    __shared__ unsigned hist[4][KMAX];
    int w = threadIdx.x >> 6;
    for (int k = threadIdx.x; k < 4 * KMAX; k += TPB1) ((unsigned*)hist)[k] = 0;
    __syncthreads();
    int base = blockIdx.x * EPB;
    #pragma unroll
    for (int i = 0; i < PERT; i++) {
        int e = base + i * TPB1 + threadIdx.x;
        if (e < E) atomicAdd(&hist[w][((unsigned)ei[e]) >> RSH], 1u);
    }
    __syncthreads();
    for (int k = threadIdx.x; k < K; k += TPB1) {
        unsigned t = hist[0][k] + hist[1][k] + hist[2][k] + hist[3][k];
        if (t) atomicAdd(&cnts[k], t);
    }
}

__global__ void scan_kernel(const unsigned* __restrict__ cnts,
                            unsigned* __restrict__ base,
                            unsigned* __restrict__ cursor, int K) {
    if (threadIdx.x == 0) {
        unsigned acc = 0;
        for (int k = 0; k < K; k++) { base[k] = acc; cursor[k] = acc; acc += cnts[k]; }
        base[K] = acc;
    }
}

__global__ __launch_bounds__(TPB1) void bin_kernel(
        const float* __restrict__ x, const float4* __restrict__ x4, int use4,
        const int* __restrict__ ei,
        const float* __restrict__ Wp1, const float* __restrict__ bp1,
        const float* __restrict__ Wp2, const float* __restrict__ consts,
        unsigned* __restrict__ cursor, uint2* __restrict__ recs, int E, int K) {
    __shared__ uint2 stage[EPB];
    __shared__ unsigned char bucket_of[EPB];
    __shared__ unsigned hist[KMAX];
    __shared__ unsigned scanv[KMAX + 1];
    __shared__ unsigned gstart[KMAX];
    __shared__ float sW1[HDIM], sb1[HDIM], sW2[HDIM];
    const float C = consts[0];
    const bool slow = (consts[1] != 0.f);
    if (slow) {
        for (int k = threadIdx.x; k < HDIM; k += TPB1) {
            sW1[k] = Wp1[k]; sb1[k] = bp1[k]; sW2[k] = Wp2[k];
        }
    }
    for (int k = threadIdx.x; k < K; k += TPB1) hist[k] = 0;
    __syncthreads();

    int base = blockIdx.x * EPB;
    uint2 rc[PERT];
    unsigned bk[PERT];
    #pragma unroll
    for (int i = 0; i < PERT; i++) {
        int e = base + i * TPB1 + threadIdx.x;
        bk[i] = 0xFFFFFFFFu;
        if (e < E) {
            int r = ei[e];
            int c = ei[(size_t)E + e];
            float dx, dy, dz;
            if (use4) {
                float4 a = x4[r], b = x4[c];
                dx = a.x - b.x; dy = a.y - b.y; dz = a.z - b.z;
            } else {
                dx = x[3*r]   - x[3*c];
                dy = x[3*r+1] - x[3*c+1];
                dz = x[3*r+2] - x[3*c+2];
            }
            float rad = sqrtf(dx*dx + dy*dy + dz*dz);
            float eo = edge_eo(rad, C, slow, sW1, sb1, sW2);
            unsigned long long u = pack_rec(dx, dy, dz, eo, (unsigned)r & (RANGE - 1));
            rc[i] = make_uint2((unsigned)u, (unsigned)(u >> 32));
            bk[i] = (unsigned)r >> RSH;
            atomicAdd(&hist[bk[i]], 1u);
        }
    }
    __syncthreads();
    if (threadIdx.x == 0) {
        unsigned a = 0;
        for (int k = 0; k < K; k++) { scanv[k] = a; a += hist[k]; }
        scanv[K] = a;
    }
    __syncthreads();
    if (threadIdx.x < (unsigned)K) {
        unsigned c_ = scanv[threadIdx.x + 1] - scanv[threadIdx.x];
        gstart[threadIdx.x] = c_ ? atomicAdd(&cursor[threadIdx.x], c_) : 0u;
    }
    for (int k = threadIdx.x; k < K; k += TPB1) hist[k] = scanv[k];
    __syncthreads();
    #pragma unroll
    for (int i = 0; i < PERT; i++) {
        if (bk[i] != 0xFFFFFFFFu) {
            unsigned slot = atomicAdd(&hist[bk[i]], 1u);
            stage[slot] = rc[i];
            bucket_of[slot] = (unsigned char)bk[i];
        }
    }
    __syncthreads();
    unsigned total = scanv[K];
    for (unsigned j = threadIdx.x; j < total; j += TPB1) {
        unsigned b_ = bucket_of[j];
        recs[(size_t)gstart[b_] + (j - scanv[b_])] = stage[j];
    }
}

__device__ __forceinline__ void proc_rec(uint2 r, unsigned (*acc)[RANGE]) {
    unsigned long long u = ((unsigned long long)r.y << 32) | r.x;
    unsigned lid = (unsigned)(u & (RANGE - 1));
    float mx = __half2float(__ushort_as_half((unsigned short)((u >> 11) & 0xFFFF)));
    float my = __half2float(__ushort_as_half((unsigned short)((u >> 27) & 0xFFFF)));
    float mz = __half2float(__ushort_as_half((unsigned short)((u >> 43) & 0xFFFF)));
    // fixed-point u32 atomics: fast int LDS path (round-5 verified)
    atomicAdd(&acc[0][lid], (unsigned)(int)__float2int_rn(mx * FIXS));
    atomicAdd(&acc[1][lid], (unsigned)(int)__float2int_rn(my * FIXS));
    atomicAdd(&acc[2][lid], (unsigned)(int)__float2int_rn(mz * FIXS));
    atomicAdd(&acc[3][lid], 1u);
}

__global__ __launch_bounds__(256) void reduce_kernel(
        const uint2* __restrict__ recs, const unsigned* __restrict__ base,
        float4* __restrict__ slices, int N, int K) {
    __shared__ unsigned acc[4][RANGE];
    int b = blockIdx.x / NSLICE;
    int s = blockIdx.x % NSLICE;
    for (int i = threadIdx.x; i < RANGE; i += 256) {
        acc[0][i] = 0u; acc[1][i] = 0u; acc[2][i] = 0u; acc[3][i] = 0u;
    }
    __syncthreads();
    unsigned lo = base[b], hi = base[b + 1];
    unsigned cnt = hi - lo;
    unsigned per = (cnt + NSLICE - 1) / NSLICE;
    unsigned st = lo + (unsigned)s * per;
    unsigned en = st + per; if (en > hi) en = hi;
    unsigned j = st + threadIdx.x;
    if (st < hi) {
        while (j + 256 < en) {
            uint2 r0 = recs[j];
            uint2 r1 = recs[j + 256];
            proc_rec(r0, acc);
            proc_rec(r1, acc);
            j += 512;
        }
        while (j < en) { proc_rec(recs[j], acc); j += 256; }
    }
    __syncthreads();
    int nbase = b * RANGE;
    for (int i = threadIdx.x; i < RANGE; i += 256) {
        int node = nbase + i;
        if (node < N)
            slices[(size_t)s * N + node] =
                make_float4((float)(int)acc[0][i] * INVFIXS,
                            (float)(int)acc[1][i] * INVFIXS,
                            (float)(int)acc[2][i] * INVFIXS,
                            (float)acc[3][i]);
    }
}

__global__ void node_kernel(const float* __restrict__ x, const float* __restrict__ vel_norm,
                            const float* __restrict__ vel,
                            const float* __restrict__ W1, const float* __restrict__ b1,
                            const float* __restrict__ W2, const float* __restrict__ b2,
                            const float4* __restrict__ slices,
                            float* __restrict__ out, int N, int S) {
    __shared__ float sW1[HDIM], sb1[HDIM], sW2[HDIM];
    for (int k = threadIdx.x; k < HDIM; k += blockDim.x) {
        sW1[k] = W1[k]; sb1[k] = b1[k]; sW2[k] = W2[k];
    }
    __syncthreads();
    int i = blockIdx.x * blockDim.x + threadIdx.x;
    if (i >= N) return;
    float sx = 0.f, sy = 0.f, sz = 0.f, sc = 0.f;
    for (int s = 0; s < S; s++) {
        float4 v = slices[(size_t)s * N + i];
        sx += v.x; sy += v.y; sz += v.z; sc += v.w;
    }
    float vn = vel_norm[i];
    float a = b2[0];
    #pragma unroll
    for (int k = 0; k < HDIM; k++) {
        float h = fmaf(vn, sW1[k], sb1[k]);
        h = (h > 0.f) ? h : LEAKY * h;
        a = fmaf(sW2[k], h, a);
    }
    float inv = 1.0f / fmaxf(sc, 1.0f);
    out[3*i]     = x[3*i]     + sx * inv + vel[3*i]     * a;
    out[3*i + 1] = x[3*i + 1] + sy * inv + vel[3*i + 1] * a;
    out[3*i + 2] = x[3*i + 2] + sz * inv + vel[3*i + 2] * a;
}

// final fallback: plain device-scope atomics
__global__ void edge_atomic_kernel(const float* __restrict__ x, const int* __restrict__ ei,
                                   const float* __restrict__ Wp1, const float* __restrict__ bp1,
                                   const float* __restrict__ Wp2, const float* __restrict__ consts,
                                   float* __restrict__ acc, int E) {
    __shared__ float sW1[HDIM], sb1[HDIM], sW2[HDIM];
    const float C = consts[0];
    const bool slow = (consts[1] != 0.f);
    if (slow) {
        for (int k = threadIdx.x; k < HDIM; k += blockDim.x) {
            sW1[k] = Wp1[k]; sb1[k] = bp1[k]; sW2[k] = Wp2[k];
        }
        __syncthreads();
    }
    int e = blockIdx.x * blockDim.x + threadIdx.x;
    if (e >= E) return;
    int r = ei[e];
    int c = ei[E + e];
    float dx = x[3*r] - x[3*c];
    float dy = x[3*r+1] - x[3*c+1];
    float dz = x[3*r+2] - x[3*c+2];
    float rad = sqrtf(dx*dx + dy*dy + dz*dz);
    float eo = edge_eo(rad, C, slow, sW1, sb1, sW2);
    float* basep = acc + ((size_t)r << 2);
    atomicAdd(basep + 0, dx * eo);
    atomicAdd(basep + 1, dy * eo);
    atomicAdd(basep + 2, dz * eo);
    atomicAdd(basep + 3, 1.f);
}

extern "C" void kernel_launch(void* const* d_in, const int* in_sizes, int n_in,
                              void* d_out, int out_size, void* d_ws, size_t ws_size,
                              hipStream_t stream) {
    const float* x        = (const float*)d_in[0];
    const float* vel_norm = (const float*)d_in[1];
    const float* vel      = (const float*)d_in[2];
    const int*   ei       = (const int*)  d_in[3];
    const float* W1       = (const float*)d_in[4];
    const float* b1       = (const float*)d_in[5];
    const float* W2       = (const float*)d_in[6];
    const float* b2       = (const float*)d_in[7];
    const float* Wp1      = (const float*)d_in[8];
    const float* bp1      = (const float*)d_in[9];
    const float* Wp2      = (const float*)d_in[10];

    const int N = in_sizes[0] / 3;
    const int E = in_sizes[3] / 2;
    const int K = (N + RANGE - 1) / RANGE;
    const int nblk = (E + EPB - 1) / EPB;

    size_t rec_bytes   = (size_t)E * sizeof(uint2);
    size_t slice_bytes = (size_t)NSLICE * N * sizeof(float4);
    size_t x4_bytes    = (size_t)N * sizeof(float4);
    size_t histG_bytes = (size_t)nblk * K * sizeof(unsigned);

    // split layout: [recs][raw | slices overlay][xh][histG][totals][base][consts]
    size_t sp_raw   = rec_bytes;
    size_t sp_x4    = sp_raw + (rec_bytes > slice_bytes ? rec_bytes : slice_bytes);
    size_t sp_hist  = sp_x4 + x4_bytes;
    size_t sp_tot   = sp_hist + histG_bytes;
    size_t sp_base  = sp_tot + (size_t)K * sizeof(unsigned);
    size_t sp_const = (sp_base + (size_t)(K + 1) * sizeof(unsigned) + 15) & ~(size_t)15;
    size_t need_split = sp_const + 32;

    // fused layout: [slices][recs][x4][small: cnts|base|cursor|consts]
    size_t small_bytes = (size_t)(KMAX + (KMAX + 1) + KMAX) * sizeof(unsigned) + 32;
    size_t fu_recs  = slice_bytes;
    size_t fu_x4    = fu_recs + rec_bytes;
    size_t fu_small = fu_x4 + x4_bytes;
    size_t need_fused = fu_small + small_bytes;

    if (K <= KMAX && ws_size >= need_split) {
        uint2*    recs   = (uint2*)   d_ws;
        uint2*    raw    = (uint2*)   ((char*)d_ws + sp_raw);
        float4*   slices = (float4*)  ((char*)d_ws + sp_raw);   // overlay: raw dead after sort
        uint2*    xh     = (uint2*)   ((char*)d_ws + sp_x4);
        unsigned* histG  = (unsigned*)((char*)d_ws + sp_hist);
        unsigned* totals = (unsigned*)((char*)d_ws + sp_tot);
        unsigned* basep  = (unsigned*)((char*)d_ws + sp_base);
        float*    consts = (float*)   ((char*)d_ws + sp_const);

        precompute_kernel<<<1, 64, 0, stream>>>(Wp1, bp1, Wp2, consts);
        repack_h_kernel<<<(N + 255) / 256, 256, 0, stream>>>(x, xh, N);
        compute_kernel<<<nblk, TPB1, 0, stream>>>(xh, ei, Wp1, bp1, Wp2, consts,
                                                  raw, histG, E, K);
        colscan_kernel<<<K, 256, 0, stream>>>(histG, totals, nblk, K);
        base_scan_kernel<<<1, 64, 0, stream>>>(totals, basep, K);
        sort_kernel<<<nblk, TPB1, 0, stream>>>(ei, raw, histG, basep, recs, E, K);
        reduce_kernel<<<K * NSLICE, 256, 0, stream>>>(recs, basep, slices, N, K);
        node_kernel<<<(N + 255) / 256, 256, 0, stream>>>(x, vel_norm, vel, W1, b1, W2, b2,
                                                         slices, (float*)d_out, N, NSLICE);
    } else if (K <= KMAX && ws_size >= need_fused) {
        float4*   slices = (float4*)  d_ws;
        uint2*    recs   = (uint2*)   ((char*)d_ws + fu_recs);
        float4*   x4     = (float4*)  ((char*)d_ws + fu_x4);
        unsigned* cnts   = (unsigned*)((char*)d_ws + fu_small);
        unsigned* basep  = cnts + KMAX;
        unsigned* cursor = basep + KMAX + 1;
        float*    consts = (float*)(cursor + KMAX);

        hipMemsetAsync(cnts, 0, small_bytes, stream);
        precompute_kernel<<<1, 64, 0, stream>>>(Wp1, bp1, Wp2, consts);
        repack_kernel<<<(N + 255) / 256, 256, 0, stream>>>(x, x4, N);
        count_kernel<<<nblk, TPB1, 0, stream>>>(ei, cnts, E, K);
        scan_kernel<<<1, 64, 0, stream>>>(cnts, basep, cursor, K);
        bin_kernel<<<nblk, TPB1, 0, stream>>>(x, x4, 1, ei, Wp1, bp1, Wp2, consts,
                                              cursor, recs, E, K);
        reduce_kernel<<<K * NSLICE, 256, 0, stream>>>(recs, basep, slices, N, K);
        node_kernel<<<(N + 255) / 256, 256, 0, stream>>>(x, vel_norm, vel, W1, b1, W2, b2,
                                                         slices, (float*)d_out, N, NSLICE);
    } else {
        float* acc    = (float*)d_ws;
        float* consts = (float*)((char*)d_ws + (size_t)N * sizeof(float4));
        hipMemsetAsync(d_ws, 0, (size_t)N * sizeof(float4) + 32, stream);
        precompute_kernel<<<1, 64, 0, stream>>>(Wp1, bp1, Wp2, consts);
        edge_atomic_kernel<<<(E + 255) / 256, 256, 0, stream>>>(x, ei, Wp1, bp1, Wp2,
                                                                consts, acc, E);
        node_kernel<<<(N + 255) / 256, 256, 0, stream>>>(x, vel_norm, vel, W1, b1, W2, b2,
                                                         (const float4*)acc, (float*)d_out, N, 1);
    }
}

// Round 12
// 210.185 us; speedup vs baseline: 1.3749x; 1.0636x over previous
//
#include <hip/hip_runtime.h>
#include <hip/hip_fp16.h>
#include <math.h>

#define LEAKY 0.2f
#define HDIM 64
#define EPB 2048            // edges per block (count, fused)
#define TPB1 256
#define PERT (EPB / TPB1)   // 8 edges per thread
#define RANGE 1024          // nodes per bucket
#define RSH 10
#define KMAX 128
#define NSLICE 12
#define FIXS 4194304.0f     // 2^22 fixed-point scale
#define INVFIXS (1.0f / 4194304.0f)

// record: bits [0,11) lid, [11,27) f16 mx, [27,43) f16 my, [43,59) f16 mz

__global__ void precompute_kernel(const float* __restrict__ Wp1,
                                  const float* __restrict__ bp1,
                                  const float* __restrict__ Wp2,
                                  float* __restrict__ consts) {
    int k = threadIdx.x;  // 64 threads == HDIM == one wave
    float w1 = Wp1[k];
    float slope = (w1 >= 0.f) ? 1.f : LEAKY;
    float c = Wp2[k] * w1 * slope;
    float bnz = (bp1[k] != 0.f) ? 1.f : 0.f;
    #pragma unroll
    for (int off = 32; off > 0; off >>= 1) {
        c += __shfl_down(c, off, 64);
        bnz += __shfl_down(bnz, off, 64);
    }
    if (k == 0) { consts[0] = c; consts[1] = bnz; }
}

// tanh(v) = 1 - 2/(exp2(v*2*log2e)+1); exact saturation, ~1e-6 rel err (R10/11-verified)
__device__ __forceinline__ float fast_tanh(float v) {
    float e = __builtin_amdgcn_exp2f(v * 2.88539008178f);
    return 1.0f - 2.0f * __builtin_amdgcn_rcpf(e + 1.0f);
}

__device__ __forceinline__ float edge_eo(float rad, float C, bool slow,
                                         const float* sW1, const float* sb1,
                                         const float* sW2) {
    if (!slow) return fast_tanh(C * rad);  // bp1==0, rad>=0: MLP collapses to linear
    float a = 0.f;
    #pragma unroll
    for (int k = 0; k < HDIM; k++) {
        float h = fmaf(rad, sW1[k], sb1[k]);
        h = (h > 0.f) ? h : LEAKY * h;
        a = fmaf(sW2[k], h, a);
    }
    return fast_tanh(a);
}

__global__ void repack_kernel(const float* __restrict__ x, float4* __restrict__ x4, int N) {
    int i = blockIdx.x * blockDim.x + threadIdx.x;
    if (i < N) x4[i] = make_float4(x[3*i], x[3*i+1], x[3*i+2], 0.f);
}

// half-packed coords: 8 B/node -> 8 nodes per 64B line (R11-verified)
__global__ void repack_h_kernel(const float* __restrict__ x, uint2* __restrict__ xh, int N) {
    int i = blockIdx.x * blockDim.x + threadIdx.x;
    if (i < N) {
        unsigned hx = __half_as_ushort(__float2half(x[3*i]));
        unsigned hy = __half_as_ushort(__float2half(x[3*i+1]));
        unsigned hz = __half_as_ushort(__float2half(x[3*i+2]));
        xh[i] = make_uint2((hy << 16) | hx, hz);
    }
}

__device__ __forceinline__ unsigned long long pack_rec(float dx, float dy, float dz,
                                                       float eo, unsigned lid) {
    unsigned hx = __half_as_ushort(__float2half(dx * eo));
    unsigned hy = __half_as_ushort(__float2half(dy * eo));
    unsigned hz = __half_as_ushort(__float2half(dz * eo));
    return (unsigned long long)lid
         | ((unsigned long long)hx << 11)
         | ((unsigned long long)hy << 27)
         | ((unsigned long long)hz << 43);
}

__device__ __forceinline__ uint2 make_record(uint2 ga, uint2 gb, int r,
                                             float C, bool slow,
                                             const float* sW1, const float* sb1,
                                             const float* sW2) {
    float ax = __half2float(__ushort_as_half((unsigned short)(ga.x & 0xFFFF)));
    float ay = __half2float(__ushort_as_half((unsigned short)(ga.x >> 16)));
    float az = __half2float(__ushort_as_half((unsigned short)(ga.y & 0xFFFF)));
    float bx = __half2float(__ushort_as_half((unsigned short)(gb.x & 0xFFFF)));
    float by = __half2float(__ushort_as_half((unsigned short)(gb.x >> 16)));
    float bz = __half2float(__ushort_as_half((unsigned short)(gb.y & 0xFFFF)));
    float dx = ax - bx, dy = ay - by, dz = az - bz;
    float rad = sqrtf(dx*dx + dy*dy + dz*dz);
    float eo = edge_eo(rad, C, slow, sW1, sb1, sW2);
    unsigned long long u = pack_rec(dx, dy, dz, eo, (unsigned)r & (RANGE - 1));
    return make_uint2((unsigned)u, (unsigned)(u >> 32));
}

// ---- count pass: per-fused-block histogram rows (rows of ei only, no global atomics)
__global__ __launch_bounds__(TPB1) void count2_kernel(const int* __restrict__ ei,
                                                      unsigned* __restrict__ histG,
                                                      int E, int K) {
    __shared__ unsigned hist[4][KMAX];
    int w = threadIdx.x >> 6;
    for (int k = threadIdx.x; k < 4 * KMAX; k += TPB1) ((unsigned*)hist)[k] = 0;
    __syncthreads();
    const size_t base = (size_t)blockIdx.x * EPB;
    if (base + EPB <= (size_t)E) {
        const int4* p = (const int4*)(ei + base);
        #pragma unroll
        for (int i = 0; i < EPB / 4 / TPB1; i++) {
            int4 v = p[threadIdx.x + i * TPB1];
            atomicAdd(&hist[w][((unsigned)v.x) >> RSH], 1u);
            atomicAdd(&hist[w][((unsigned)v.y) >> RSH], 1u);
            atomicAdd(&hist[w][((unsigned)v.z) >> RSH], 1u);
            atomicAdd(&hist[w][((unsigned)v.w) >> RSH], 1u);
        }
    } else {
        for (size_t e = base + threadIdx.x; e < (size_t)E; e += TPB1)
            atomicAdd(&hist[w][((unsigned)ei[e]) >> RSH], 1u);
    }
    __syncthreads();
    for (int k = threadIdx.x; k < K; k += TPB1)
        histG[(size_t)blockIdx.x * K + k] = hist[0][k] + hist[1][k] + hist[2][k] + hist[3][k];
}

// one block per bucket b: exclusive prefix over blocks of histG[.][b] (in place) + totals[b]
__global__ __launch_bounds__(256) void colscan_kernel(unsigned* __restrict__ histG,
                                                      unsigned* __restrict__ totals,
                                                      int nblk, int K) {
    __shared__ unsigned pa[256], pb[256];
    const int b = blockIdx.x;
    const int t = threadIdx.x;
    const int chunk = (nblk + 255) / 256;
    const int r0 = t * chunk;
    unsigned s = 0;
    for (int i = 0; i < chunk; i++) {
        int r = r0 + i;
        if (r < nblk) s += histG[(size_t)r * K + b];
    }
    pa[t] = s;
    __syncthreads();
    unsigned* src = pa; unsigned* dst = pb;
    for (int off = 1; off < 256; off <<= 1) {
        unsigned v = src[t];
        if (t >= off) v += src[t - off];
        dst[t] = v;
        __syncthreads();
        unsigned* tmp = src; src = dst; dst = tmp;
    }
    unsigned excl = (t > 0) ? src[t - 1] : 0u;
    if (t == 255) totals[b] = src[255];
    unsigned run = excl;
    for (int i = 0; i < chunk; i++) {
        int r = r0 + i;
        if (r < nblk) {
            size_t a = (size_t)r * K + b;
            unsigned v = histG[a];
            histG[a] = run;
            run += v;
        }
    }
}

__global__ void base_scan_kernel(const unsigned* __restrict__ totals,
                                 unsigned* __restrict__ base, int K) {
    if (threadIdx.x == 0) {
        unsigned acc = 0;
        for (int k = 0; k < K; k++) { base[k] = acc; acc += totals[k]; }
        base[K] = acc;
    }
}

// ---- FUSED compute+sort: R11 gather front-end + R5/R9-verified LDS sort back-end.
// Writes bucket-contiguous records directly; no raw round-trip, no cursor atomics.
__global__ __launch_bounds__(TPB1) void fused_kernel(
        const uint2* __restrict__ xh,
        const int* __restrict__ ei,
        const float* __restrict__ Wp1, const float* __restrict__ bp1,
        const float* __restrict__ Wp2, const float* __restrict__ consts,
        const unsigned* __restrict__ histG, const unsigned* __restrict__ basep,
        uint2* __restrict__ recs, int E, int K) {
    __shared__ uint2 stage[EPB];                 // 16 KB
    __shared__ unsigned char bucket_of[EPB];     // 2 KB
    __shared__ unsigned hist[KMAX];
    __shared__ unsigned scanv[KMAX + 1];
    __shared__ unsigned gstart[KMAX];
    __shared__ float sW1[HDIM], sb1[HDIM], sW2[HDIM];
    const float C = consts[0];
    const bool slow = (consts[1] != 0.f);
    if (slow) {
        for (int k = threadIdx.x; k < HDIM; k += TPB1) {
            sW1[k] = Wp1[k]; sb1[k] = bp1[k]; sW2[k] = Wp2[k];
        }
    }
    for (int k = threadIdx.x; k < K; k += TPB1) hist[k] = 0;
    __syncthreads();

    const size_t base = (size_t)blockIdx.x * EPB;
    const unsigned t = threadIdx.x;
    uint2 rc[PERT];
    unsigned bk[PERT];
    if (base + EPB <= (size_t)E && (E & 3) == 0) {
        const int4* pr = (const int4*)(ei + base);
        const int4* pc = (const int4*)(ei + (size_t)E + base);
        #pragma unroll
        for (int i = 0; i < PERT / 4; i++) {
            unsigned idx = t + i * TPB1;
            int4 rv = pr[idx];
            int4 cv = pc[idx];
            // batched gathers as scalars (R11-verified: no spill)
            uint2 ga0 = xh[rv.x], gb0 = xh[cv.x];
            uint2 ga1 = xh[rv.y], gb1 = xh[cv.y];
            uint2 ga2 = xh[rv.z], gb2 = xh[cv.z];
            uint2 ga3 = xh[rv.w], gb3 = xh[cv.w];
            rc[i*4 + 0] = make_record(ga0, gb0, rv.x, C, slow, sW1, sb1, sW2);
            rc[i*4 + 1] = make_record(ga1, gb1, rv.y, C, slow, sW1, sb1, sW2);
            rc[i*4 + 2] = make_record(ga2, gb2, rv.z, C, slow, sW1, sb1, sW2);
            rc[i*4 + 3] = make_record(ga3, gb3, rv.w, C, slow, sW1, sb1, sW2);
            bk[i*4 + 0] = (unsigned)rv.x >> RSH;
            bk[i*4 + 1] = (unsigned)rv.y >> RSH;
            bk[i*4 + 2] = (unsigned)rv.z >> RSH;
            bk[i*4 + 3] = (unsigned)rv.w >> RSH;
            atomicAdd(&hist[bk[i*4 + 0]], 1u);
            atomicAdd(&hist[bk[i*4 + 1]], 1u);
            atomicAdd(&hist[bk[i*4 + 2]], 1u);
            atomicAdd(&hist[bk[i*4 + 3]], 1u);
        }
    } else {
        #pragma unroll
        for (int i = 0; i < PERT; i++) {
            size_t e = base + (size_t)i * TPB1 + t;
            bk[i] = 0xFFFFFFFFu;
            if (e < (size_t)E) {
                int r = ei[e];
                int c = ei[(size_t)E + e];
                uint2 ga = xh[r], gb = xh[c];
                rc[i] = make_record(ga, gb, r, C, slow, sW1, sb1, sW2);
                bk[i] = (unsigned)r >> RSH;
                atomicAdd(&hist[bk[i]], 1u);
            }
        }
    }
    __syncthreads();
    // serial scan (R7-verified; ~K dependent LDS reads, once per block)
    if (t == 0) {
        unsigned a = 0;
        for (int k = 0; k < K; k++) { scanv[k] = a; a += hist[k]; }
        scanv[K] = a;
    }
    __syncthreads();
    // deterministic global offsets (R9-verified, no cursor atomics)
    if (t < (unsigned)K)
        gstart[t] = basep[t] + histG[(size_t)blockIdx.x * K + t];
    for (int k = t; k < K; k += TPB1) hist[k] = scanv[k];  // running cursors
    __syncthreads();
    // phase-2 scatter into stage (R5-verified rank atomic)
    #pragma unroll
    for (int i = 0; i < PERT; i++) {
        if (bk[i] != 0xFFFFFFFFu) {
            unsigned slot = atomicAdd(&hist[bk[i]], 1u);
            stage[slot] = rc[i];
            bucket_of[slot] = (unsigned char)bk[i];
        }
    }
    __syncthreads();
    // coalesced write-out to bucket-contiguous positions (R9-verified)
    unsigned total = scanv[K];
    for (unsigned j = t; j < total; j += TPB1) {
        unsigned b_ = bucket_of[j];
        recs[(size_t)gstart[b_] + (j - scanv[b_])] = stage[j];
    }
}

// ---- fused fallback (R7-verified, with cursor atomics) ----
__global__ __launch_bounds__(TPB1) void count_kernel(const int* __restrict__ ei,
                                                     unsigned* __restrict__ cnts,
                                                     int E, int K) {
    __shared__ unsigned hist[4][KMAX];
    int w = threadIdx.x >> 6;
    for (int k = threadIdx.x; k < 4 * KMAX; k += TPB1) ((unsigned*)hist)[k] = 0;
    __syncthreads();
    int base = blockIdx.x * EPB;
    #pragma unroll
    for (int i = 0; i < PERT; i++) {
        int e = base + i * TPB1 + threadIdx.x;
        if (e < E) atomicAdd(&hist[w][((unsigned)ei[e]) >> RSH], 1u);
    }
    __syncthreads();
    for (int k = threadIdx.x; k < K; k += TPB1) {
        unsigned t = hist[0][k] + hist[1][k] + hist[2][k] + hist[3][k];
        if (t) atomicAdd(&cnts[k], t);
    }
}

__global__ void scan_kernel(const unsigned* __restrict__ cnts,
                            unsigned* __restrict__ base,
                            unsigned* __restrict__ cursor, int K) {
    if (threadIdx.x == 0) {
        unsigned acc = 0;
        for (int k = 0; k < K; k++) { base[k] = acc; cursor[k] = acc; acc += cnts[k]; }
        base[K] = acc;
    }
}

__global__ __launch_bounds__(TPB1) void bin_kernel(
        const float* __restrict__ x, const float4* __restrict__ x4, int use4,
        const int* __restrict__ ei,
        const float* __restrict__ Wp1, const float* __restrict__ bp1,
        const float* __restrict__ Wp2, const float* __restrict__ consts,
        unsigned* __restrict__ cursor, uint2* __restrict__ recs, int E, int K) {
    __shared__ uint2 stage[EPB];
    __shared__ unsigned char bucket_of[EPB];
    __shared__ unsigned hist[KMAX];
    __shared__ unsigned scanv[KMAX + 1];
    __shared__ unsigned gstart[KMAX];
    __shared__ float sW1[HDIM], sb1[HDIM], sW2[HDIM];
    const float C = consts[0];
    const bool slow = (consts[1] != 0.f);
    if (slow) {
        for (int k = threadIdx.x; k < HDIM; k += TPB1) {
            sW1[k] = Wp1[k]; sb1[k] = bp1[k]; sW2[k] = Wp2[k];
        }
    }
    for (int k = threadIdx.x; k < K; k += TPB1) hist[k] = 0;
    __syncthreads();

    int base = blockIdx.x * EPB;
    uint2 rc[PERT];
    unsigned bk[PERT];
    #pragma unroll
    for (int i = 0; i < PERT; i++) {
        int e = base + i * TPB1 + threadIdx.x;
        bk[i] = 0xFFFFFFFFu;
        if (e < E) {
            int r = ei[e];
            int c = ei[(size_t)E + e];
            float dx, dy, dz;
            if (use4) {
                float4 a = x4[r], b = x4[c];
                dx = a.x - b.x; dy = a.y - b.y; dz = a.z - b.z;
            } else {
                dx = x[3*r]   - x[3*c];
                dy = x[3*r+1] - x[3*c+1];
                dz = x[3*r+2] - x[3*c+2];
            }
            float rad = sqrtf(dx*dx + dy*dy + dz*dz);
            float eo = edge_eo(rad, C, slow, sW1, sb1, sW2);
            unsigned long long u = pack_rec(dx, dy, dz, eo, (unsigned)r & (RANGE - 1));
            rc[i] = make_uint2((unsigned)u, (unsigned)(u >> 32));
            bk[i] = (unsigned)r >> RSH;
            atomicAdd(&hist[bk[i]], 1u);
        }
    }
    __syncthreads();
    if (threadIdx.x == 0) {
        unsigned a = 0;
        for (int k = 0; k < K; k++) { scanv[k] = a; a += hist[k]; }
        scanv[K] = a;
    }
    __syncthreads();
    if (threadIdx.x < (unsigned)K) {
        unsigned c_ = scanv[threadIdx.x + 1] - scanv[threadIdx.x];
        gstart[threadIdx.x] = c_ ? atomicAdd(&cursor[threadIdx.x], c_) : 0u;
    }
    for (int k = threadIdx.x; k < K; k += TPB1) hist[k] = scanv[k];
    __syncthreads();
    #pragma unroll
    for (int i = 0; i < PERT; i++) {
        if (bk[i] != 0xFFFFFFFFu) {
            unsigned slot = atomicAdd(&hist[bk[i]], 1u);
            stage[slot] = rc[i];
            bucket_of[slot] = (unsigned char)bk[i];
        }
    }
    __syncthreads();
    unsigned total = scanv[K];
    for (unsigned j = threadIdx.x; j < total; j += TPB1) {
        unsigned b_ = bucket_of[j];
        recs[(size_t)gstart[b_] + (j - scanv[b_])] = stage[j];
    }
}

__device__ __forceinline__ void proc_rec(uint2 r, unsigned (*acc)[RANGE]) {
    unsigned long long u = ((unsigned long long)r.y << 32) | r.x;
    unsigned lid = (unsigned)(u & (RANGE - 1));
    float mx = __half2float(__ushort_as_half((unsigned short)((u >> 11) & 0xFFFF)));
    float my = __half2float(__ushort_as_half((unsigned short)((u >> 27) & 0xFFFF)));
    float mz = __half2float(__ushort_as_half((unsigned short)((u >> 43) & 0xFFFF)));
    // fixed-point u32 atomics: fast int LDS path (round-5 verified)
    atomicAdd(&acc[0][lid], (unsigned)(int)__float2int_rn(mx * FIXS));
    atomicAdd(&acc[1][lid], (unsigned)(int)__float2int_rn(my * FIXS));
    atomicAdd(&acc[2][lid], (unsigned)(int)__float2int_rn(mz * FIXS));
    atomicAdd(&acc[3][lid], 1u);
}

__global__ __launch_bounds__(256) void reduce_kernel(
        const uint2* __restrict__ recs, const unsigned* __restrict__ base,
        float4* __restrict__ slices, int N, int K) {
    __shared__ unsigned acc[4][RANGE];
    int b = blockIdx.x / NSLICE;
    int s = blockIdx.x % NSLICE;
    for (int i = threadIdx.x; i < RANGE; i += 256) {
        acc[0][i] = 0u; acc[1][i] = 0u; acc[2][i] = 0u; acc[3][i] = 0u;
    }
    __syncthreads();
    unsigned lo = base[b], hi = base[b + 1];
    unsigned cnt = hi - lo;
    unsigned per = (cnt + NSLICE - 1) / NSLICE;
    unsigned st = lo + (unsigned)s * per;
    unsigned en = st + per; if (en > hi) en = hi;
    unsigned j = st + threadIdx.x;
    if (st < hi) {
        while (j + 256 < en) {
            uint2 r0 = recs[j];
            uint2 r1 = recs[j + 256];
            proc_rec(r0, acc);
            proc_rec(r1, acc);
            j += 512;
        }
        while (j < en) { proc_rec(recs[j], acc); j += 256; }
    }
    __syncthreads();
    int nbase = b * RANGE;
    for (int i = threadIdx.x; i < RANGE; i += 256) {
        int node = nbase + i;
        if (node < N)
            slices[(size_t)s * N + node] =
                make_float4((float)(int)acc[0][i] * INVFIXS,
                            (float)(int)acc[1][i] * INVFIXS,
                            (float)(int)acc[2][i] * INVFIXS,
                            (float)acc[3][i]);
    }
}

__global__ void node_kernel(const float* __restrict__ x, const float* __restrict__ vel_norm,
                            const float* __restrict__ vel,
                            const float* __restrict__ W1, const float* __restrict__ b1,
                            const float* __restrict__ W2, const float* __restrict__ b2,
                            const float4* __restrict__ slices,
                            float* __restrict__ out, int N, int S) {
    __shared__ float sW1[HDIM], sb1[HDIM], sW2[HDIM];
    for (int k = threadIdx.x; k < HDIM; k += blockDim.x) {
        sW1[k] = W1[k]; sb1[k] = b1[k]; sW2[k] = W2[k];
    }
    __syncthreads();
    int i = blockIdx.x * blockDim.x + threadIdx.x;
    if (i >= N) return;
    float sx = 0.f, sy = 0.f, sz = 0.f, sc = 0.f;
    for (int s = 0; s < S; s++) {
        float4 v = slices[(size_t)s * N + i];
        sx += v.x; sy += v.y; sz += v.z; sc += v.w;
    }
    float vn = vel_norm[i];
    float a = b2[0];
    #pragma unroll
    for (int k = 0; k < HDIM; k++) {
        float h = fmaf(vn, sW1[k], sb1[k]);
        h = (h > 0.f) ? h : LEAKY * h;
        a = fmaf(sW2[k], h, a);
    }
    float inv = 1.0f / fmaxf(sc, 1.0f);
    out[3*i]     = x[3*i]     + sx * inv + vel[3*i]     * a;
    out[3*i + 1] = x[3*i + 1] + sy * inv + vel[3*i + 1] * a;
    out[3*i + 2] = x[3*i + 2] + sz * inv + vel[3*i + 2] * a;
}

// final fallback: plain device-scope atomics
__global__ void edge_atomic_kernel(const float* __restrict__ x, const int* __restrict__ ei,
                                   const float* __restrict__ Wp1, const float* __restrict__ bp1,
                                   const float* __restrict__ Wp2, const float* __restrict__ consts,
                                   float* __restrict__ acc, int E) {
    __shared__ float sW1[HDIM], sb1[HDIM], sW2[HDIM];
    const float C = consts[0];
    const bool slow = (consts[1] != 0.f);
    if (slow) {
        for (int k = threadIdx.x; k < HDIM; k += blockDim.x) {
            sW1[k] = Wp1[k]; sb1[k] = bp1[k]; sW2[k] = Wp2[k];
        }
        __syncthreads();
    }
    int e = blockIdx.x * blockDim.x + threadIdx.x;
    if (e >= E) return;
    int r = ei[e];
    int c = ei[E + e];
    float dx = x[3*r] - x[3*c];
    float dy = x[3*r+1] - x[3*c+1];
    float dz = x[3*r+2] - x[3*c+2];
    float rad = sqrtf(dx*dx + dy*dy + dz*dz);
    float eo = edge_eo(rad, C, slow, sW1, sb1, sW2);
    float* basep = acc + ((size_t)r << 2);
    atomicAdd(basep + 0, dx * eo);
    atomicAdd(basep + 1, dy * eo);
    atomicAdd(basep + 2, dz * eo);
    atomicAdd(basep + 3, 1.f);
}

extern "C" void kernel_launch(void* const* d_in, const int* in_sizes, int n_in,
                              void* d_out, int out_size, void* d_ws, size_t ws_size,
                              hipStream_t stream) {
    const float* x        = (const float*)d_in[0];
    const float* vel_norm = (const float*)d_in[1];
    const float* vel      = (const float*)d_in[2];
    const int*   ei       = (const int*)  d_in[3];
    const float* W1       = (const float*)d_in[4];
    const float* b1       = (const float*)d_in[5];
    const float* W2       = (const float*)d_in[6];
    const float* b2       = (const float*)d_in[7];
    const float* Wp1      = (const float*)d_in[8];
    const float* bp1      = (const float*)d_in[9];
    const float* Wp2      = (const float*)d_in[10];

    const int N = in_sizes[0] / 3;
    const int E = in_sizes[3] / 2;
    const int K = (N + RANGE - 1) / RANGE;
    const int nblk = (E + EPB - 1) / EPB;

    size_t rec_bytes   = (size_t)E * sizeof(uint2);
    size_t slice_bytes = (size_t)NSLICE * N * sizeof(float4);
    size_t x4_bytes    = (size_t)N * sizeof(float4);
    size_t histG_bytes = (size_t)nblk * K * sizeof(unsigned);

    // fused-split layout: [recs][slices][xh][histG][totals][base][consts]  (no raw buffer)
    size_t sp_slices = rec_bytes;
    size_t sp_xh     = sp_slices + slice_bytes;
    size_t sp_hist   = sp_xh + x4_bytes;          // xh needs only N*8, reserve x4 size for safety
    size_t sp_tot    = sp_hist + histG_bytes;
    size_t sp_base   = sp_tot + (size_t)K * sizeof(unsigned);
    size_t sp_const  = (sp_base + (size_t)(K + 1) * sizeof(unsigned) + 15) & ~(size_t)15;
    size_t need_split = sp_const + 32;

    // fused fallback layout: [slices][recs][x4][small: cnts|base|cursor|consts]
    size_t small_bytes = (size_t)(KMAX + (KMAX + 1) + KMAX) * sizeof(unsigned) + 32;
    size_t fu_recs  = slice_bytes;
    size_t fu_x4    = fu_recs + rec_bytes;
    size_t fu_small = fu_x4 + x4_bytes;
    size_t need_fused = fu_small + small_bytes;

    if (K <= KMAX && ws_size >= need_split) {
        uint2*    recs   = (uint2*)   d_ws;
        float4*   slices = (float4*)  ((char*)d_ws + sp_slices);
        uint2*    xh     = (uint2*)   ((char*)d_ws + sp_xh);
        unsigned* histG  = (unsigned*)((char*)d_ws + sp_hist);
        unsigned* totals = (unsigned*)((char*)d_ws + sp_tot);
        unsigned* basep  = (unsigned*)((char*)d_ws + sp_base);
        float*    consts = (float*)   ((char*)d_ws + sp_const);

        precompute_kernel<<<1, 64, 0, stream>>>(Wp1, bp1, Wp2, consts);
        repack_h_kernel<<<(N + 255) / 256, 256, 0, stream>>>(x, xh, N);
        count2_kernel<<<nblk, TPB1, 0, stream>>>(ei, histG, E, K);
        colscan_kernel<<<K, 256, 0, stream>>>(histG, totals, nblk, K);
        base_scan_kernel<<<1, 64, 0, stream>>>(totals, basep, K);
        fused_kernel<<<nblk, TPB1, 0, stream>>>(xh, ei, Wp1, bp1, Wp2, consts,
                                                histG, basep, recs, E, K);
        reduce_kernel<<<K * NSLICE, 256, 0, stream>>>(recs, basep, slices, N, K);
        node_kernel<<<(N + 255) / 256, 256, 0, stream>>>(x, vel_norm, vel, W1, b1, W2, b2,
                                                         slices, (float*)d_out, N, NSLICE);
    } else if (K <= KMAX && ws_size >= need_fused) {
        float4*   slices = (float4*)  d_ws;
        uint2*    recs   = (uint2*)   ((char*)d_ws + fu_recs);
        float4*   x4     = (float4*)  ((char*)d_ws + fu_x4);
        unsigned* cnts   = (unsigned*)((char*)d_ws + fu_small);
        unsigned* basep  = cnts + KMAX;
        unsigned* cursor = basep + KMAX + 1;
        float*    consts = (float*)(cursor + KMAX);

        hipMemsetAsync(cnts, 0, small_bytes, stream);
        precompute_kernel<<<1, 64, 0, stream>>>(Wp1, bp1, Wp2, consts);
        repack_kernel<<<(N + 255) / 256, 256, 0, stream>>>(x, x4, N);
        count_kernel<<<nblk, TPB1, 0, stream>>>(ei, cnts, E, K);
        scan_kernel<<<1, 64, 0, stream>>>(cnts, basep, cursor, K);
        bin_kernel<<<nblk, TPB1, 0, stream>>>(x, x4, 1, ei, Wp1, bp1, Wp2, consts,
                                              cursor, recs, E, K);
        reduce_kernel<<<K * NSLICE, 256, 0, stream>>>(recs, basep, slices, N, K);
        node_kernel<<<(N + 255) / 256, 256, 0, stream>>>(x, vel_norm, vel, W1, b1, W2, b2,
                                                         slices, (float*)d_out, N, NSLICE);
    } else {
        float* acc    = (float*)d_ws;
        float* consts = (float*)((char*)d_ws + (size_t)N * sizeof(float4));
        hipMemsetAsync(d_ws, 0, (size_t)N * sizeof(float4) + 32, stream);
        precompute_kernel<<<1, 64, 0, stream>>>(Wp1, bp1, Wp2, consts);
        edge_atomic_kernel<<<(E + 255) / 256, 256, 0, stream>>>(x, ei, Wp1, bp1, Wp2,
                                                                consts, acc, E);
        node_kernel<<<(N + 255) / 256, 256, 0, stream>>>(x, vel_norm, vel, W1, b1, W2, b2,
                                                         (const float4*)acc, (float*)d_out, N, 1);
    }
}

// Round 13
// 199.864 us; speedup vs baseline: 1.4459x; 1.0516x over previous
//
#include <hip/hip_runtime.h>
#include <hip/hip_fp16.h>
#include <math.h>

#define LEAKY 0.2f
#define HDIM 64
#define EPB 2048            // edges per block (count, fused)
#define TPB1 256
#define PERT (EPB / TPB1)   // 8 edges per thread
#define RANGE 1024          // nodes per bucket
#define RSH 10
#define KMAX 128
#define NSLICE 12
#define FIXS 4194304.0f     // 2^22 fixed-point scale
#define INVFIXS (1.0f / 4194304.0f)

// record: bits [0,11) lid, [11,27) f16 mx, [27,43) f16 my, [43,59) f16 mz

// tanh(v) = 1 - 2/(exp2(v*2*log2e)+1); exact saturation, ~1e-6 rel err (R10/11-verified)
__device__ __forceinline__ float fast_tanh(float v) {
    float e = __builtin_amdgcn_exp2f(v * 2.88539008178f);
    return 1.0f - 2.0f * __builtin_amdgcn_rcpf(e + 1.0f);
}

__device__ __forceinline__ float edge_eo(float rad, float C, bool slow,
                                         const float* sW1, const float* sb1,
                                         const float* sW2) {
    if (!slow) return fast_tanh(C * rad);  // bp1==0, rad>=0: MLP collapses to linear
    float a = 0.f;
    #pragma unroll
    for (int k = 0; k < HDIM; k++) {
        float h = fmaf(rad, sW1[k], sb1[k]);
        h = (h > 0.f) ? h : LEAKY * h;
        a = fmaf(sW2[k], h, a);
    }
    return fast_tanh(a);
}

__global__ void repack_kernel(const float* __restrict__ x, float4* __restrict__ x4, int N) {
    int i = blockIdx.x * blockDim.x + threadIdx.x;
    if (i < N) x4[i] = make_float4(x[3*i], x[3*i+1], x[3*i+2], 0.f);
}

// half-packed coords (R11-verified) + precompute folded into block 0 (R13: -1 dispatch)
__global__ void repack_h_kernel(const float* __restrict__ x, uint2* __restrict__ xh, int N,
                                const float* __restrict__ Wp1, const float* __restrict__ bp1,
                                const float* __restrict__ Wp2, float* __restrict__ consts) {
    int i = blockIdx.x * blockDim.x + threadIdx.x;
    if (i < N) {
        unsigned hx = __half_as_ushort(__float2half(x[3*i]));
        unsigned hy = __half_as_ushort(__float2half(x[3*i+1]));
        unsigned hz = __half_as_ushort(__float2half(x[3*i+2]));
        xh[i] = make_uint2((hy << 16) | hx, hz);
    }
    if (blockIdx.x == 0 && threadIdx.x < 64) {
        int k = threadIdx.x;   // one wave: shuffle reduction valid
        float w1 = Wp1[k];
        float slope = (w1 >= 0.f) ? 1.f : LEAKY;
        float c = Wp2[k] * w1 * slope;
        float bnz = (bp1[k] != 0.f) ? 1.f : 0.f;
        #pragma unroll
        for (int off = 32; off > 0; off >>= 1) {
            c += __shfl_down(c, off, 64);
            bnz += __shfl_down(bnz, off, 64);
        }
        if (k == 0) { consts[0] = c; consts[1] = bnz; }
    }
}

__device__ __forceinline__ unsigned long long pack_rec(float dx, float dy, float dz,
                                                       float eo, unsigned lid) {
    unsigned hx = __half_as_ushort(__float2half(dx * eo));
    unsigned hy = __half_as_ushort(__float2half(dy * eo));
    unsigned hz = __half_as_ushort(__float2half(dz * eo));
    return (unsigned long long)lid
         | ((unsigned long long)hx << 11)
         | ((unsigned long long)hy << 27)
         | ((unsigned long long)hz << 43);
}

__device__ __forceinline__ uint2 make_record(uint2 ga, uint2 gb, int r,
                                             float C, bool slow,
                                             const float* sW1, const float* sb1,
                                             const float* sW2) {
    float ax = __half2float(__ushort_as_half((unsigned short)(ga.x & 0xFFFF)));
    float ay = __half2float(__ushort_as_half((unsigned short)(ga.x >> 16)));
    float az = __half2float(__ushort_as_half((unsigned short)(ga.y & 0xFFFF)));
    float bx = __half2float(__ushort_as_half((unsigned short)(gb.x & 0xFFFF)));
    float by = __half2float(__ushort_as_half((unsigned short)(gb.x >> 16)));
    float bz = __half2float(__ushort_as_half((unsigned short)(gb.y & 0xFFFF)));
    float dx = ax - bx, dy = ay - by, dz = az - bz;
    float rad = sqrtf(dx*dx + dy*dy + dz*dz);
    float eo = edge_eo(rad, C, slow, sW1, sb1, sW2);
    unsigned long long u = pack_rec(dx, dy, dz, eo, (unsigned)r & (RANGE - 1));
    return make_uint2((unsigned)u, (unsigned)(u >> 32));
}

// ---- count pass: per-fused-block histogram rows (rows of ei only, no global atomics)
__global__ __launch_bounds__(TPB1) void count2_kernel(const int* __restrict__ ei,
                                                      unsigned* __restrict__ histG,
                                                      int E, int K) {
    __shared__ unsigned hist[4][KMAX];
    int w = threadIdx.x >> 6;
    for (int k = threadIdx.x; k < 4 * KMAX; k += TPB1) ((unsigned*)hist)[k] = 0;
    __syncthreads();
    const size_t base = (size_t)blockIdx.x * EPB;
    if (base + EPB <= (size_t)E) {
        const int4* p = (const int4*)(ei + base);
        #pragma unroll
        for (int i = 0; i < EPB / 4 / TPB1; i++) {
            int4 v = p[threadIdx.x + i * TPB1];
            atomicAdd(&hist[w][((unsigned)v.x) >> RSH], 1u);
            atomicAdd(&hist[w][((unsigned)v.y) >> RSH], 1u);
            atomicAdd(&hist[w][((unsigned)v.z) >> RSH], 1u);
            atomicAdd(&hist[w][((unsigned)v.w) >> RSH], 1u);
        }
    } else {
        for (size_t e = base + threadIdx.x; e < (size_t)E; e += TPB1)
            atomicAdd(&hist[w][((unsigned)ei[e]) >> RSH], 1u);
    }
    __syncthreads();
    for (int k = threadIdx.x; k < K; k += TPB1)
        histG[(size_t)blockIdx.x * K + k] = hist[0][k] + hist[1][k] + hist[2][k] + hist[3][k];
}

// one block per bucket b: exclusive prefix over blocks of histG[.][b] (in place) + totals[b]
__global__ __launch_bounds__(256) void colscan_kernel(unsigned* __restrict__ histG,
                                                      unsigned* __restrict__ totals,
                                                      int nblk, int K) {
    __shared__ unsigned pa[256], pb[256];
    const int b = blockIdx.x;
    const int t = threadIdx.x;
    const int chunk = (nblk + 255) / 256;
    const int r0 = t * chunk;
    unsigned s = 0;
    for (int i = 0; i < chunk; i++) {
        int r = r0 + i;
        if (r < nblk) s += histG[(size_t)r * K + b];
    }
    pa[t] = s;
    __syncthreads();
    unsigned* src = pa; unsigned* dst = pb;
    for (int off = 1; off < 256; off <<= 1) {
        unsigned v = src[t];
        if (t >= off) v += src[t - off];
        dst[t] = v;
        __syncthreads();
        unsigned* tmp = src; src = dst; dst = tmp;
    }
    unsigned excl = (t > 0) ? src[t - 1] : 0u;
    if (t == 255) totals[b] = src[255];
    unsigned run = excl;
    for (int i = 0; i < chunk; i++) {
        int r = r0 + i;
        if (r < nblk) {
            size_t a = (size_t)r * K + b;
            unsigned v = histG[a];
            histG[a] = run;
            run += v;
        }
    }
}

// ---- FUSED compute+sort (R12-verified) with 16-gather batching + local base prefix
__global__ __launch_bounds__(TPB1) void fused_kernel(
        const uint2* __restrict__ xh,
        const int* __restrict__ ei,
        const float* __restrict__ Wp1, const float* __restrict__ bp1,
        const float* __restrict__ Wp2, const float* __restrict__ consts,
        const unsigned* __restrict__ histG, const unsigned* __restrict__ totals,
        uint2* __restrict__ recs, int E, int K) {
    __shared__ uint2 stage[EPB];                 // 16 KB
    __shared__ unsigned char bucket_of[EPB];     // 2 KB
    __shared__ unsigned hist[KMAX];
    __shared__ unsigned scanv[KMAX + 1];
    __shared__ unsigned gstart[KMAX];
    __shared__ unsigned sbase[KMAX + 1];
    __shared__ float sW1[HDIM], sb1[HDIM], sW2[HDIM];
    const float C = consts[0];
    const bool slow = (consts[1] != 0.f);
    if (slow) {
        for (int k = threadIdx.x; k < HDIM; k += TPB1) {
            sW1[k] = Wp1[k]; sb1[k] = bp1[k]; sW2[k] = Wp2[k];
        }
    }
    for (int k = threadIdx.x; k < K; k += TPB1) hist[k] = 0;
    if (threadIdx.x < (unsigned)K) sbase[threadIdx.x] = totals[threadIdx.x];
    __syncthreads();

    const size_t base = (size_t)blockIdx.x * EPB;
    const unsigned t = threadIdx.x;
    uint2 rc[PERT];
    unsigned bk[PERT];
    if (base + EPB <= (size_t)E && (E & 3) == 0) {
        const int4* pr = (const int4*)(ei + base);
        const int4* pc = (const int4*)(ei + (size_t)E + base);
        // two index quads, then ALL 16 gathers in flight before first use (MLP)
        int4 rv0 = pr[t];
        int4 rv1 = pr[t + TPB1];
        int4 cv0 = pc[t];
        int4 cv1 = pc[t + TPB1];
        uint2 ga0 = xh[rv0.x], ga1 = xh[rv0.y], ga2 = xh[rv0.z], ga3 = xh[rv0.w];
        uint2 ga4 = xh[rv1.x], ga5 = xh[rv1.y], ga6 = xh[rv1.z], ga7 = xh[rv1.w];
        uint2 gb0 = xh[cv0.x], gb1 = xh[cv0.y], gb2 = xh[cv0.z], gb3 = xh[cv0.w];
        uint2 gb4 = xh[cv1.x], gb5 = xh[cv1.y], gb6 = xh[cv1.z], gb7 = xh[cv1.w];
        rc[0] = make_record(ga0, gb0, rv0.x, C, slow, sW1, sb1, sW2);
        rc[1] = make_record(ga1, gb1, rv0.y, C, slow, sW1, sb1, sW2);
        rc[2] = make_record(ga2, gb2, rv0.z, C, slow, sW1, sb1, sW2);
        rc[3] = make_record(ga3, gb3, rv0.w, C, slow, sW1, sb1, sW2);
        rc[4] = make_record(ga4, gb4, rv1.x, C, slow, sW1, sb1, sW2);
        rc[5] = make_record(ga5, gb5, rv1.y, C, slow, sW1, sb1, sW2);
        rc[6] = make_record(ga6, gb6, rv1.z, C, slow, sW1, sb1, sW2);
        rc[7] = make_record(ga7, gb7, rv1.w, C, slow, sW1, sb1, sW2);
        bk[0] = (unsigned)rv0.x >> RSH; bk[1] = (unsigned)rv0.y >> RSH;
        bk[2] = (unsigned)rv0.z >> RSH; bk[3] = (unsigned)rv0.w >> RSH;
        bk[4] = (unsigned)rv1.x >> RSH; bk[5] = (unsigned)rv1.y >> RSH;
        bk[6] = (unsigned)rv1.z >> RSH; bk[7] = (unsigned)rv1.w >> RSH;
        #pragma unroll
        for (int i = 0; i < PERT; i++) atomicAdd(&hist[bk[i]], 1u);
    } else {
        #pragma unroll
        for (int i = 0; i < PERT; i++) {
            size_t e = base + (size_t)i * TPB1 + t;
            bk[i] = 0xFFFFFFFFu;
            if (e < (size_t)E) {
                int r = ei[e];
                int c = ei[(size_t)E + e];
                uint2 ga = xh[r], gb = xh[c];
                rc[i] = make_record(ga, gb, r, C, slow, sW1, sb1, sW2);
                bk[i] = (unsigned)r >> RSH;
                atomicAdd(&hist[bk[i]], 1u);
            }
        }
    }
    __syncthreads();
    // serial scans (R7-verified): local hist + global bucket bases from totals
    if (t == 0) {
        unsigned a = 0;
        for (int k = 0; k < K; k++) { scanv[k] = a; a += hist[k]; }
        scanv[K] = a;
    } else if (t == 64) {  // separate wave: overlap the two serial scans
        unsigned a = 0;
        for (int k = 0; k < K; k++) { unsigned v = sbase[k]; sbase[k] = a; a += v; }
        sbase[K] = a;
    }
    __syncthreads();
    if (t < (unsigned)K)
        gstart[t] = sbase[t] + histG[(size_t)blockIdx.x * K + t];
    for (int k = t; k < K; k += TPB1) hist[k] = scanv[k];  // running cursors
    __syncthreads();
    // phase-2 scatter into stage (R5-verified rank atomic)
    #pragma unroll
    for (int i = 0; i < PERT; i++) {
        if (bk[i] != 0xFFFFFFFFu) {
            unsigned slot = atomicAdd(&hist[bk[i]], 1u);
            stage[slot] = rc[i];
            bucket_of[slot] = (unsigned char)bk[i];
        }
    }
    __syncthreads();
    // coalesced write-out to bucket-contiguous positions (R9-verified)
    unsigned total = scanv[K];
    for (unsigned j = t; j < total; j += TPB1) {
        unsigned b_ = bucket_of[j];
        recs[(size_t)gstart[b_] + (j - scanv[b_])] = stage[j];
    }
}

// ---- fused fallback (R7-verified, with cursor atomics) ----
__global__ __launch_bounds__(TPB1) void count_kernel(const int* __restrict__ ei,
                                                     unsigned* __restrict__ cnts,
                                                     int E, int K) {
    __shared__ unsigned hist[4][KMAX];
    int w = threadIdx.x >> 6;
    for (int k = threadIdx.x; k < 4 * KMAX; k += TPB1) ((unsigned*)hist)[k] = 0;
    __syncthreads();
    int base = blockIdx.x * EPB;
    #pragma unroll
    for (int i = 0; i < PERT; i++) {
        int e = base + i * TPB1 + threadIdx.x;
        if (e < E) atomicAdd(&hist[w][((unsigned)ei[e]) >> RSH], 1u);
    }
    __syncthreads();
    for (int k = threadIdx.x; k < K; k += TPB1) {
        unsigned t = hist[0][k] + hist[1][k] + hist[2][k] + hist[3][k];
        if (t) atomicAdd(&cnts[k], t);
    }
}

__global__ void scan_kernel(const unsigned* __restrict__ cnts,
                            unsigned* __restrict__ base,
                            unsigned* __restrict__ cursor, int K) {
    if (threadIdx.x == 0) {
        unsigned acc = 0;
        for (int k = 0; k < K; k++) { base[k] = acc; cursor[k] = acc; acc += cnts[k]; }
        base[K] = acc;
    }
}

__global__ void precompute_kernel(const float* __restrict__ Wp1,
                                  const float* __restrict__ bp1,
                                  const float* __restrict__ Wp2,
                                  float* __restrict__ consts) {
    int k = threadIdx.x;
    float w1 = Wp1[k];
    float slope = (w1 >= 0.f) ? 1.f : LEAKY;
    float c = Wp2[k] * w1 * slope;
    float bnz = (bp1[k] != 0.f) ? 1.f : 0.f;
    #pragma unroll
    for (int off = 32; off > 0; off >>= 1) {
        c += __shfl_down(c, off, 64);
        bnz += __shfl_down(bnz, off, 64);
    }
    if (k == 0) { consts[0] = c; consts[1] = bnz; }
}

__global__ __launch_bounds__(TPB1) void bin_kernel(
        const float* __restrict__ x, const float4* __restrict__ x4, int use4,
        const int* __restrict__ ei,
        const float* __restrict__ Wp1, const float* __restrict__ bp1,
        const float* __restrict__ Wp2, const float* __restrict__ consts,
        unsigned* __restrict__ cursor, uint2* __restrict__ recs, int E, int K) {
    __shared__ uint2 stage[EPB];
    __shared__ unsigned char bucket_of[EPB];
    __shared__ unsigned hist[KMAX];
    __shared__ unsigned scanv[KMAX + 1];
    __shared__ unsigned gstart[KMAX];
    __shared__ float sW1[HDIM], sb1[HDIM], sW2[HDIM];
    const float C = consts[0];
    const bool slow = (consts[1] != 0.f);
    if (slow) {
        for (int k = threadIdx.x; k < HDIM; k += TPB1) {
            sW1[k] = Wp1[k]; sb1[k] = bp1[k]; sW2[k] = Wp2[k];
        }
    }
    for (int k = threadIdx.x; k < K; k += TPB1) hist[k] = 0;
    __syncthreads();

    int base = blockIdx.x * EPB;
    uint2 rc[PERT];
    unsigned bk[PERT];
    #pragma unroll
    for (int i = 0; i < PERT; i++) {
        int e = base + i * TPB1 + threadIdx.x;
        bk[i] = 0xFFFFFFFFu;
        if (e < E) {
            int r = ei[e];
            int c = ei[(size_t)E + e];
            float dx, dy, dz;
            if (use4) {
                float4 a = x4[r], b = x4[c];
                dx = a.x - b.x; dy = a.y - b.y; dz = a.z - b.z;
            } else {
                dx = x[3*r]   - x[3*c];
                dy = x[3*r+1] - x[3*c+1];
                dz = x[3*r+2] - x[3*c+2];
            }
            float rad = sqrtf(dx*dx + dy*dy + dz*dz);
            float eo = edge_eo(rad, C, slow, sW1, sb1, sW2);
            unsigned long long u = pack_rec(dx, dy, dz, eo, (unsigned)r & (RANGE - 1));
            rc[i] = make_uint2((unsigned)u, (unsigned)(u >> 32));
            bk[i] = (unsigned)r >> RSH;
            atomicAdd(&hist[bk[i]], 1u);
        }
    }
    __syncthreads();
    if (threadIdx.x == 0) {
        unsigned a = 0;
        for (int k = 0; k < K; k++) { scanv[k] = a; a += hist[k]; }
        scanv[K] = a;
    }
    __syncthreads();
    if (threadIdx.x < (unsigned)K) {
        unsigned c_ = scanv[threadIdx.x + 1] - scanv[threadIdx.x];
        gstart[threadIdx.x] = c_ ? atomicAdd(&cursor[threadIdx.x], c_) : 0u;
    }
    for (int k = threadIdx.x; k < K; k += TPB1) hist[k] = scanv[k];
    __syncthreads();
    #pragma unroll
    for (int i = 0; i < PERT; i++) {
        if (bk[i] != 0xFFFFFFFFu) {
            unsigned slot = atomicAdd(&hist[bk[i]], 1u);
            stage[slot] = rc[i];
            bucket_of[slot] = (unsigned char)bk[i];
        }
    }
    __syncthreads();
    unsigned total = scanv[K];
    for (unsigned j = threadIdx.x; j < total; j += TPB1) {
        unsigned b_ = bucket_of[j];
        recs[(size_t)gstart[b_] + (j - scanv[b_])] = stage[j];
    }
}

__device__ __forceinline__ void proc_rec(uint2 r, unsigned (*acc)[RANGE]) {
    unsigned long long u = ((unsigned long long)r.y << 32) | r.x;
    unsigned lid = (unsigned)(u & (RANGE - 1));
    float mx = __half2float(__ushort_as_half((unsigned short)((u >> 11) & 0xFFFF)));
    float my = __half2float(__ushort_as_half((unsigned short)((u >> 27) & 0xFFFF)));
    float mz = __half2float(__ushort_as_half((unsigned short)((u >> 43) & 0xFFFF)));
    // fixed-point u32 atomics: fast int LDS path (round-5 verified)
    atomicAdd(&acc[0][lid], (unsigned)(int)__float2int_rn(mx * FIXS));
    atomicAdd(&acc[1][lid], (unsigned)(int)__float2int_rn(my * FIXS));
    atomicAdd(&acc[2][lid], (unsigned)(int)__float2int_rn(mz * FIXS));
    atomicAdd(&acc[3][lid], 1u);
}

// totals-based: each block derives base[b], base[b+1] locally (R13: removes base_scan)
__global__ __launch_bounds__(256) void reduce_kernel(
        const uint2* __restrict__ recs, const unsigned* __restrict__ totals,
        float4* __restrict__ slices, int N, int K) {
    __shared__ unsigned acc[4][RANGE];
    __shared__ unsigned sbase[KMAX + 1];
    int b = blockIdx.x / NSLICE;
    int s = blockIdx.x % NSLICE;
    if (threadIdx.x < (unsigned)K) sbase[threadIdx.x] = totals[threadIdx.x];
    for (int i = threadIdx.x; i < RANGE; i += 256) {
        acc[0][i] = 0u; acc[1][i] = 0u; acc[2][i] = 0u; acc[3][i] = 0u;
    }
    __syncthreads();
    if (threadIdx.x == 0) {
        unsigned a = 0;
        for (int k = 0; k < K; k++) { unsigned v = sbase[k]; sbase[k] = a; a += v; }
        sbase[K] = a;
    }
    __syncthreads();
    unsigned lo = sbase[b], hi = sbase[b + 1];
    unsigned cnt = hi - lo;
    unsigned per = (cnt + NSLICE - 1) / NSLICE;
    unsigned st = lo + (unsigned)s * per;
    unsigned en = st + per; if (en > hi) en = hi;
    unsigned j = st + threadIdx.x;
    if (st < hi) {
        while (j + 256 < en) {
            uint2 r0 = recs[j];
            uint2 r1 = recs[j + 256];
            proc_rec(r0, acc);
            proc_rec(r1, acc);
            j += 512;
        }
        while (j < en) { proc_rec(recs[j], acc); j += 256; }
    }
    __syncthreads();
    int nbase = b * RANGE;
    for (int i = threadIdx.x; i < RANGE; i += 256) {
        int node = nbase + i;
        if (node < N)
            slices[(size_t)s * N + node] =
                make_float4((float)(int)acc[0][i] * INVFIXS,
                            (float)(int)acc[1][i] * INVFIXS,
                            (float)(int)acc[2][i] * INVFIXS,
                            (float)acc[3][i]);
    }
}

__global__ void node_kernel(const float* __restrict__ x, const float* __restrict__ vel_norm,
                            const float* __restrict__ vel,
                            const float* __restrict__ W1, const float* __restrict__ b1,
                            const float* __restrict__ W2, const float* __restrict__ b2,
                            const float4* __restrict__ slices,
                            float* __restrict__ out, int N, int S) {
    __shared__ float sW1[HDIM], sb1[HDIM], sW2[HDIM];
    for (int k = threadIdx.x; k < HDIM; k += blockDim.x) {
        sW1[k] = W1[k]; sb1[k] = b1[k]; sW2[k] = W2[k];
    }
    __syncthreads();
    int i = blockIdx.x * blockDim.x + threadIdx.x;
    if (i >= N) return;
    float sx = 0.f, sy = 0.f, sz = 0.f, sc = 0.f;
    for (int s = 0; s < S; s++) {
        float4 v = slices[(size_t)s * N + i];
        sx += v.x; sy += v.y; sz += v.z; sc += v.w;
    }
    float vn = vel_norm[i];
    float a = b2[0];
    #pragma unroll
    for (int k = 0; k < HDIM; k++) {
        float h = fmaf(vn, sW1[k], sb1[k]);
        h = (h > 0.f) ? h : LEAKY * h;
        a = fmaf(sW2[k], h, a);
    }
    float inv = 1.0f / fmaxf(sc, 1.0f);
    out[3*i]     = x[3*i]     + sx * inv + vel[3*i]     * a;
    out[3*i + 1] = x[3*i + 1] + sy * inv + vel[3*i + 1] * a;
    out[3*i + 2] = x[3*i + 2] + sz * inv + vel[3*i + 2] * a;
}

// reduce variant for fallback path (basep array form, R12-verified)
__global__ __launch_bounds__(256) void reduce_basep_kernel(
        const uint2* __restrict__ recs, const unsigned* __restrict__ base,
        float4* __restrict__ slices, int N, int K) {
    __shared__ unsigned acc[4][RANGE];
    int b = blockIdx.x / NSLICE;
    int s = blockIdx.x % NSLICE;
    for (int i = threadIdx.x; i < RANGE; i += 256) {
        acc[0][i] = 0u; acc[1][i] = 0u; acc[2][i] = 0u; acc[3][i] = 0u;
    }
    __syncthreads();
    unsigned lo = base[b], hi = base[b + 1];
    unsigned cnt = hi - lo;
    unsigned per = (cnt + NSLICE - 1) / NSLICE;
    unsigned st = lo + (unsigned)s * per;
    unsigned en = st + per; if (en > hi) en = hi;
    unsigned j = st + threadIdx.x;
    if (st < hi) {
        while (j + 256 < en) {
            uint2 r0 = recs[j];
            uint2 r1 = recs[j + 256];
            proc_rec(r0, acc);
            proc_rec(r1, acc);
            j += 512;
        }
        while (j < en) { proc_rec(recs[j], acc); j += 256; }
    }
    __syncthreads();
    int nbase = b * RANGE;
    for (int i = threadIdx.x; i < RANGE; i += 256) {
        int node = nbase + i;
        if (node < N)
            slices[(size_t)s * N + node] =
                make_float4((float)(int)acc[0][i] * INVFIXS,
                            (float)(int)acc[1][i] * INVFIXS,
                            (float)(int)acc[2][i] * INVFIXS,
                            (float)acc[3][i]);
    }
}

// final fallback: plain device-scope atomics
__global__ void edge_atomic_kernel(const float* __restrict__ x, const int* __restrict__ ei,
                                   const float* __restrict__ Wp1, const float* __restrict__ bp1,
                                   const float* __restrict__ Wp2, const float* __restrict__ consts,
                                   float* __restrict__ acc, int E) {
    __shared__ float sW1[HDIM], sb1[HDIM], sW2[HDIM];
    const float C = consts[0];
    const bool slow = (consts[1] != 0.f);
    if (slow) {
        for (int k = threadIdx.x; k < HDIM; k += blockDim.x) {
            sW1[k] = Wp1[k]; sb1[k] = bp1[k]; sW2[k] = Wp2[k];
        }
        __syncthreads();
    }
    int e = blockIdx.x * blockDim.x + threadIdx.x;
    if (e >= E) return;
    int r = ei[e];
    int c = ei[E + e];
    float dx = x[3*r] - x[3*c];
    float dy = x[3*r+1] - x[3*c+1];
    float dz = x[3*r+2] - x[3*c+2];
    float rad = sqrtf(dx*dx + dy*dy + dz*dz);
    float eo = edge_eo(rad, C, slow, sW1, sb1, sW2);
    float* basep = acc + ((size_t)r << 2);
    atomicAdd(basep + 0, dx * eo);
    atomicAdd(basep + 1, dy * eo);
    atomicAdd(basep + 2, dz * eo);
    atomicAdd(basep + 3, 1.f);
}

extern "C" void kernel_launch(void* const* d_in, const int* in_sizes, int n_in,
                              void* d_out, int out_size, void* d_ws, size_t ws_size,
                              hipStream_t stream) {
    const float* x        = (const float*)d_in[0];
    const float* vel_norm = (const float*)d_in[1];
    const float* vel      = (const float*)d_in[2];
    const int*   ei       = (const int*)  d_in[3];
    const float* W1       = (const float*)d_in[4];
    const float* b1       = (const float*)d_in[5];
    const float* W2       = (const float*)d_in[6];
    const float* b2       = (const float*)d_in[7];
    const float* Wp1      = (const float*)d_in[8];
    const float* bp1      = (const float*)d_in[9];
    const float* Wp2      = (const float*)d_in[10];

    const int N = in_sizes[0] / 3;
    const int E = in_sizes[3] / 2;
    const int K = (N + RANGE - 1) / RANGE;
    const int nblk = (E + EPB - 1) / EPB;

    size_t rec_bytes   = (size_t)E * sizeof(uint2);
    size_t slice_bytes = (size_t)NSLICE * N * sizeof(float4);
    size_t x4_bytes    = (size_t)N * sizeof(float4);
    size_t histG_bytes = (size_t)nblk * K * sizeof(unsigned);

    // split layout: [recs][slices][xh][histG][totals][consts]
    size_t sp_slices = rec_bytes;
    size_t sp_xh     = sp_slices + slice_bytes;
    size_t sp_hist   = sp_xh + x4_bytes;
    size_t sp_tot    = sp_hist + histG_bytes;
    size_t sp_const  = (sp_tot + (size_t)(K + 1) * sizeof(unsigned) + 15) & ~(size_t)15;
    size_t need_split = sp_const + 32;

    // fallback layout: [slices][recs][x4][small: cnts|base|cursor|consts]
    size_t small_bytes = (size_t)(KMAX + (KMAX + 1) + KMAX) * sizeof(unsigned) + 32;
    size_t fu_recs  = slice_bytes;
    size_t fu_x4    = fu_recs + rec_bytes;
    size_t fu_small = fu_x4 + x4_bytes;
    size_t need_fused = fu_small + small_bytes;

    if (K <= KMAX && ws_size >= need_split) {
        uint2*    recs   = (uint2*)   d_ws;
        float4*   slices = (float4*)  ((char*)d_ws + sp_slices);
        uint2*    xh     = (uint2*)   ((char*)d_ws + sp_xh);
        unsigned* histG  = (unsigned*)((char*)d_ws + sp_hist);
        unsigned* totals = (unsigned*)((char*)d_ws + sp_tot);
        float*    consts = (float*)   ((char*)d_ws + sp_const);

        repack_h_kernel<<<(N + 255) / 256, 256, 0, stream>>>(x, xh, N, Wp1, bp1, Wp2, consts);
        count2_kernel<<<nblk, TPB1, 0, stream>>>(ei, histG, E, K);
        colscan_kernel<<<K, 256, 0, stream>>>(histG, totals, nblk, K);
        fused_kernel<<<nblk, TPB1, 0, stream>>>(xh, ei, Wp1, bp1, Wp2, consts,
                                                histG, totals, recs, E, K);
        reduce_kernel<<<K * NSLICE, 256, 0, stream>>>(recs, totals, slices, N, K);
        node_kernel<<<(N + 255) / 256, 256, 0, stream>>>(x, vel_norm, vel, W1, b1, W2, b2,
                                                         slices, (float*)d_out, N, NSLICE);
    } else if (K <= KMAX && ws_size >= need_fused) {
        float4*   slices = (float4*)  d_ws;
        uint2*    recs   = (uint2*)   ((char*)d_ws + fu_recs);
        float4*   x4     = (float4*)  ((char*)d_ws + fu_x4);
        unsigned* cnts   = (unsigned*)((char*)d_ws + fu_small);
        unsigned* basep  = cnts + KMAX;
        unsigned* cursor = basep + KMAX + 1;
        float*    consts = (float*)(cursor + KMAX);

        hipMemsetAsync(cnts, 0, small_bytes, stream);
        precompute_kernel<<<1, 64, 0, stream>>>(Wp1, bp1, Wp2, consts);
        repack_kernel<<<(N + 255) / 256, 256, 0, stream>>>(x, x4, N);
        count_kernel<<<nblk, TPB1, 0, stream>>>(ei, cnts, E, K);
        scan_kernel<<<1, 64, 0, stream>>>(cnts, basep, cursor, K);
        bin_kernel<<<nblk, TPB1, 0, stream>>>(x, x4, 1, ei, Wp1, bp1, Wp2, consts,
                                              cursor, recs, E, K);
        reduce_basep_kernel<<<K * NSLICE, 256, 0, stream>>>(recs, basep, slices, N, K);
        node_kernel<<<(N + 255) / 256, 256, 0, stream>>>(x, vel_norm, vel, W1, b1, W2, b2,
                                                         slices, (float*)d_out, N, NSLICE);
    } else {
        float* acc    = (float*)d_ws;
        float* consts = (float*)((char*)d_ws + (size_t)N * sizeof(float4));
        hipMemsetAsync(d_ws, 0, (size_t)N * sizeof(float4) + 32, stream);
        precompute_kernel<<<1, 64, 0, stream>>>(Wp1, bp1, Wp2, consts);
        edge_atomic_kernel<<<(E + 255) / 256, 256, 0, stream>>>(x, ei, Wp1, bp1, Wp2,
                                                                consts, acc, E);
        node_kernel<<<(N + 255) / 256, 256, 0, stream>>>(x, vel_norm, vel, W1, b1, W2, b2,
                                                         (const float4*)acc, (float*)d_out, N, 1);
    }
}